// Round 3
// baseline (1157.957 us; speedup 1.0000x reference)
//
#include <hip/hip_runtime.h>
#include <hip/hip_bf16.h>

#define NFEAT 128
#define NHID  256
#define NCLASS 40
#define THRESH 0.1f
#define FEPS   1e-8f

__device__ __forceinline__ float waveSum(float v) {
#pragma unroll
    for (int off = 32; off > 0; off >>= 1) v += __shfl_xor(v, off, 64);
    return v;
}

// ---- row norms, F=128 (wave per node, float2 per lane) ----
__global__ void k_norm128(const float* __restrict__ v, float* __restrict__ nrm, int N) {
    int wid = (blockIdx.x * blockDim.x + threadIdx.x) >> 6;
    int lane = threadIdx.x & 63;
    if (wid >= N) return;
    const float2* r = (const float2*)(v + (size_t)wid * NFEAT);
    float2 a = r[lane];
    float s = waveSum(a.x * a.x + a.y * a.y);
    if (lane == 0) nrm[wid] = fmaxf(sqrtf(s), FEPS);
}

// ---- row norms, F=256 (wave per node, float4 per lane) ----
__global__ void k_norm256(const float* __restrict__ v, float* __restrict__ nrm, int N) {
    int wid = (blockIdx.x * blockDim.x + threadIdx.x) >> 6;
    int lane = threadIdx.x & 63;
    if (wid >= N) return;
    const float4* r = (const float4*)(v + (size_t)wid * NHID);
    float4 a = r[lane];
    float s = waveSum(a.x * a.x + a.y * a.y + a.z * a.z + a.w * a.w);
    if (lane == 0) nrm[wid] = fmaxf(sqrtf(s), FEPS);
}

// ---- att1: per-edge cosine sim on x, edge weight + deg accumulation ----
__global__ void k_att1(const float* __restrict__ xf,
                       const int* __restrict__ row, const int* __restrict__ col,
                       const float* __restrict__ nrm,
                       float* __restrict__ w1, float* __restrict__ deg, int E) {
    int e = (blockIdx.x * blockDim.x + threadIdx.x) >> 6;
    int lane = threadIdx.x & 63;
    if (e >= E) return;
    int r = row[e], c = col[e];
    const float2* xr = (const float2*)(xf + (size_t)r * NFEAT);
    const float2* xc = (const float2*)(xf + (size_t)c * NFEAT);
    float2 a = xr[lane], b = xc[lane];
    float s = waveSum(a.x * b.x + a.y * b.y);
    if (lane == 0) {
        float sims = s / (nrm[r] * nrm[c]);
        float w = (sims >= THRESH && r != c) ? sims : 0.0f;
        w1[e] = w;
        if (w != 0.0f) unsafeAtomicAdd(&deg[r], w);
    }
}

// ---- deg -> 1/sqrt(1+deg), in place ----
__global__ void k_dinv(float* __restrict__ d, int N) {
    int i = blockIdx.x * blockDim.x + threadIdx.x;
    if (i < N) d[i] = 1.0f / sqrtf(1.0f + d[i]);
}

// ---- layer1 aggregation in feature space: xagg[row] += norm * x[col] ----
__global__ void k_agg1(const float* __restrict__ xf,
                       const int* __restrict__ row, const int* __restrict__ col,
                       const float* __restrict__ w1, const float* __restrict__ dinv,
                       float* __restrict__ xagg, int E) {
    int e = (blockIdx.x * blockDim.x + threadIdx.x) >> 6;
    int lane = threadIdx.x & 63;
    if (e >= E) return;
    float w = w1[e];
    if (w == 0.0f) return;
    int r = row[e], c = col[e];
    float nm = dinv[r] * w * dinv[c];
    const float2* src = (const float2*)(xf + (size_t)c * NFEAT);
    float2 v = src[lane];
    float* dst = xagg + (size_t)r * NFEAT + lane * 2;
    unsafeAtomicAdd(dst + 0, nm * v.x);
    unsafeAtomicAdd(dst + 1, nm * v.y);
}

// ---- self-loop in feature space: xagg += dinv^2 * x ----
__global__ void k_self(const float* __restrict__ xf, const float* __restrict__ dinv,
                       float* __restrict__ xagg, int n) {
    int idx = blockIdx.x * blockDim.x + threadIdx.x;
    if (idx >= n) return;
    int i = idx >> 7;  // / NFEAT
    float d = dinv[i];
    xagg[idx] += d * d * xf[idx];
}

// ---- h = relu(xagg @ W1 + b1): 8 nodes per 256-thread block ----
__global__ __launch_bounds__(256) void k_gemm1h(const float* __restrict__ xagg,
                                                const float* __restrict__ W1f,
                                                const float* __restrict__ b1f,
                                                float* __restrict__ h, int N) {
    __shared__ float xs[8][NFEAT];
    int i0 = blockIdx.x * 8;
    int tid = threadIdx.x;
    for (int idx = tid; idx < 8 * NFEAT; idx += 256) {
        int n = idx >> 7, k = idx & 127;
        int i = i0 + n;
        xs[n][k] = (i < N) ? xagg[(size_t)i * NFEAT + k] : 0.0f;
    }
    __syncthreads();
    int j = tid;
    float acc[8] = {0.f, 0.f, 0.f, 0.f, 0.f, 0.f, 0.f, 0.f};
#pragma unroll 4
    for (int k = 0; k < NFEAT; ++k) {
        float wv = W1f[(size_t)k * NHID + j];
#pragma unroll
        for (int n = 0; n < 8; ++n) acc[n] += xs[n][k] * wv;
    }
    float bj = b1f[j];
#pragma unroll
    for (int n = 0; n < 8; ++n) {
        int i = i0 + n;
        if (i < N) h[(size_t)i * NHID + j] = fmaxf(acc[n] + bj, 0.0f);
    }
}

// ---- att2: cosine sim on h, gated by mask1 (w1 != 0) ----
__global__ void k_att2(const float* __restrict__ h,
                       const int* __restrict__ row, const int* __restrict__ col,
                       const float* __restrict__ nrm2, const float* __restrict__ w1,
                       float* __restrict__ w2e, float* __restrict__ deg, int E) {
    int e = (blockIdx.x * blockDim.x + threadIdx.x) >> 6;
    int lane = threadIdx.x & 63;
    if (e >= E) return;
    float w1v = w1[e];
    if (w1v == 0.0f) { if (lane == 0) w2e[e] = 0.0f; return; }
    int r = row[e], c = col[e];
    const float4* hr = (const float4*)(h + (size_t)r * NHID);
    const float4* hc = (const float4*)(h + (size_t)c * NHID);
    float4 a = hr[lane], b = hc[lane];
    float s = waveSum(a.x * b.x + a.y * b.y + a.z * b.z + a.w * b.w);
    if (lane == 0) {
        float sims = s / (nrm2[r] * nrm2[c]);
        float w = (sims >= THRESH) ? sims : 0.0f;  // r != c implied by w1v != 0
        w2e[e] = w;
        if (w != 0.0f) unsafeAtomicAdd(&deg[r], w);
    }
}

// ---- g = h @ W2 (4 nodes/block, 64-thread group per node, W2 in LDS) ----
__global__ __launch_bounds__(256) void k_gemm2(const float* __restrict__ h,
                                               const float* __restrict__ W2f,
                                               float* __restrict__ g, int N) {
    __shared__ float w2s[NHID * NCLASS];  // 40 KB
    int tid = threadIdx.x;
    for (int idx = tid; idx < NHID * NCLASS; idx += 256) w2s[idx] = W2f[idx];
    __syncthreads();
    int grp = tid >> 6, j = tid & 63;
    int i = blockIdx.x * 4 + grp;
    if (i >= N || j >= NCLASS) return;
    const float* hr = h + (size_t)i * NHID;
    float acc = 0.0f;
#pragma unroll 4
    for (int k = 0; k < NHID; ++k) acc += hr[k] * w2s[k * NCLASS + j];
    g[(size_t)i * NCLASS + j] = acc;
}

// ---- out init = dinv2^2 * g + b2 (full overwrite of poisoned d_out) ----
__global__ void k_selfout(const float* __restrict__ g, const float* __restrict__ dinv2,
                          const float* __restrict__ b2f, float* __restrict__ out, int n) {
    int idx = blockIdx.x * blockDim.x + threadIdx.x;
    if (idx >= n) return;
    int i = idx / NCLASS, j = idx - i * NCLASS;
    float d = dinv2[i];
    out[idx] = d * d * g[idx] + b2f[j];
}

// ---- scatter2: out[row] += norm * g[col] (wave per edge, 40 active lanes) ----
__global__ void k_scatter2(const float* __restrict__ g,
                           const int* __restrict__ row, const int* __restrict__ col,
                           const float* __restrict__ w2e, const float* __restrict__ dinv2,
                           float* __restrict__ out, int E) {
    int e = (blockIdx.x * blockDim.x + threadIdx.x) >> 6;
    int lane = threadIdx.x & 63;
    if (e >= E) return;
    float w = w2e[e];
    if (w == 0.0f || lane >= NCLASS) return;
    int r = row[e], c = col[e];
    float nm = dinv2[r] * w * dinv2[c];
    unsafeAtomicAdd(&out[(size_t)r * NCLASS + lane], nm * g[(size_t)c * NCLASS + lane]);
}

extern "C" void kernel_launch(void* const* d_in, const int* in_sizes, int n_in,
                              void* d_out, int out_size, void* d_ws, size_t ws_size,
                              hipStream_t stream) {
    const float* x  = (const float*)d_in[0];
    const int* row  = (const int*)d_in[1];
    const int* col  = (const int*)d_in[2];
    const float* W1 = (const float*)d_in[3];
    const float* b1 = (const float*)d_in[4];
    const float* W2 = (const float*)d_in[5];
    const float* b2 = (const float*)d_in[6];
    float* out = (float*)d_out;
    const int N = in_sizes[0] / NFEAT;
    const int E = in_sizes[1];

    // ---- workspace layout (~162.4 MB peak) ----
    char* ws = (char*)d_ws;
    size_t off = 0;
    auto alloc = [&](size_t bytes) {
        char* p = ws + off;
        off += (bytes + 255) & ~(size_t)255;
        return p;
    };
    float* xagg  = (float*)alloc((size_t)N * NFEAT * 4);   // 51.2 MB; g reuses after gemm1h
    float* h     = (float*)alloc((size_t)N * NHID * 4);    // 102.4 MB
    float* w1buf = (float*)alloc((size_t)E * 4);           // 4 MB
    float* w2buf = (float*)alloc((size_t)E * 4);           // 4 MB
    float* nrm   = (float*)alloc((size_t)N * 4);           // nrm1, later nrm2
    float* deg   = (float*)alloc((size_t)N * 4);           // degsum/dinv, both layers
    float* g     = xagg;                                   // 16 MB (xagg dead after gemm1h)

    const int eBlocks = (E + 3) / 4;    // 4 edge-waves per 256-thread block
    const int nBlocks4 = (N + 3) / 4;

    // ---- layer 1 ----
    hipMemsetAsync(deg, 0, (size_t)N * 4, stream);
    k_norm128<<<nBlocks4, 256, 0, stream>>>(x, nrm, N);
    k_att1<<<eBlocks, 256, 0, stream>>>(x, row, col, nrm, w1buf, deg, E);
    k_dinv<<<(N + 255) / 256, 256, 0, stream>>>(deg, N);
    hipMemsetAsync(xagg, 0, (size_t)N * NFEAT * 4, stream);
    k_agg1<<<eBlocks, 256, 0, stream>>>(x, row, col, w1buf, deg, xagg, E);
    k_self<<<(N * NFEAT + 255) / 256, 256, 0, stream>>>(x, deg, xagg, N * NFEAT);
    k_gemm1h<<<(N + 7) / 8, 256, 0, stream>>>(xagg, W1, b1, h, N);

    // ---- layer 2 ----
    k_norm256<<<nBlocks4, 256, 0, stream>>>(h, nrm, N);
    hipMemsetAsync(deg, 0, (size_t)N * 4, stream);
    k_att2<<<eBlocks, 256, 0, stream>>>(h, row, col, nrm, w1buf, w2buf, deg, E);
    k_dinv<<<(N + 255) / 256, 256, 0, stream>>>(deg, N);
    k_gemm2<<<nBlocks4, 256, 0, stream>>>(h, W2, g, N);
    k_selfout<<<(N * NCLASS + 255) / 256, 256, 0, stream>>>(g, deg, b2, out, N * NCLASS);
    k_scatter2<<<eBlocks, 256, 0, stream>>>(g, row, col, w2buf, deg, out, E);
}

// Round 4
// 926.529 us; speedup vs baseline: 1.2498x; 1.2498x over previous
//
#include <hip/hip_runtime.h>
#include <hip/hip_bf16.h>
#include <hip/hip_fp16.h>

#define NFEAT 128
#define NHID  256
#define NCLASS 40
#define THRESH 0.1f
#define FEPS   1e-8f

__device__ __forceinline__ float waveSum(float v) {
#pragma unroll
    for (int off = 32; off > 0; off >>= 1) v += __shfl_xor(v, off, 64);
    return v;
}

// butterfly over 32-lane half (offsets < 32 stay within each half)
__device__ __forceinline__ float halfSum(float v) {
#pragma unroll
    for (int off = 16; off > 0; off >>= 1) v += __shfl_xor(v, off, 64);
    return v;
}

// ---- row norms, F=128 (wave per node, float2 per lane) ----
__global__ void k_norm128(const float* __restrict__ v, float* __restrict__ nrm, int N) {
    int wid = (blockIdx.x * blockDim.x + threadIdx.x) >> 6;
    int lane = threadIdx.x & 63;
    if (wid >= N) return;
    const float2* r = (const float2*)(v + (size_t)wid * NFEAT);
    float2 a = r[lane];
    float s = waveSum(a.x * a.x + a.y * a.y);
    if (lane == 0) nrm[wid] = fmaxf(sqrtf(s), FEPS);
}

// ---- att1: 2 edges per wave; 32 lanes x float4 = 128 floats per row ----
__global__ void k_att1(const float* __restrict__ xf,
                       const int* __restrict__ row, const int* __restrict__ col,
                       const float* __restrict__ nrm,
                       float* __restrict__ w1, float* __restrict__ deg, int E) {
    int wid = (blockIdx.x * blockDim.x + threadIdx.x) >> 6;
    int lane = threadIdx.x & 63;
    int half = lane >> 5, l32 = lane & 31;
    int e = wid * 2 + half;
    if (e >= E) return;
    int r = row[e], c = col[e];
    float4 a = ((const float4*)(xf + (size_t)r * NFEAT))[l32];
    float4 b = ((const float4*)(xf + (size_t)c * NFEAT))[l32];
    float s = halfSum(a.x * b.x + a.y * b.y + a.z * b.z + a.w * b.w);
    if (l32 == 0) {
        float sims = s / (nrm[r] * nrm[c]);
        float w = (sims >= THRESH && r != c) ? sims : 0.0f;
        w1[e] = w;
        if (w != 0.0f) unsafeAtomicAdd(&deg[r], w);
    }
}

// ---- deg -> 1/sqrt(1+deg), in place ----
__global__ void k_dinv(float* __restrict__ d, int N) {
    int i = blockIdx.x * blockDim.x + threadIdx.x;
    if (i < N) d[i] = 1.0f / sqrtf(1.0f + d[i]);
}

// ---- xagg = dinv^2 * x (replaces memset + separate self-loop pass) ----
__global__ void k_selfinit(const float* __restrict__ xf, const float* __restrict__ dinv,
                           float* __restrict__ xagg, int n) {
    int idx = blockIdx.x * blockDim.x + threadIdx.x;
    if (idx >= n) return;
    int i = idx >> 7;  // / NFEAT
    float d = dinv[i];
    xagg[idx] = d * d * xf[idx];
}

// ---- agg1: 2 edges per wave; xagg[row] += norm * x[col] ----
__global__ void k_agg1(const float* __restrict__ xf,
                       const int* __restrict__ row, const int* __restrict__ col,
                       const float* __restrict__ w1, const float* __restrict__ dinv,
                       float* __restrict__ xagg, int E) {
    int wid = (blockIdx.x * blockDim.x + threadIdx.x) >> 6;
    int lane = threadIdx.x & 63;
    int half = lane >> 5, l32 = lane & 31;
    int e = wid * 2 + half;
    if (e >= E) return;
    float w = w1[e];
    if (w == 0.0f) return;
    int r = row[e], c = col[e];
    float nm = dinv[r] * w * dinv[c];
    float4 v = ((const float4*)(xf + (size_t)c * NFEAT))[l32];
    float* dst = xagg + (size_t)r * NFEAT + l32 * 4;
    unsafeAtomicAdd(dst + 0, nm * v.x);
    unsafeAtomicAdd(dst + 1, nm * v.y);
    unsafeAtomicAdd(dst + 2, nm * v.z);
    unsafeAtomicAdd(dst + 3, nm * v.w);
}

// ---- h = relu(xagg @ W1 + b1), 16 nodes/block, fused row-norm of h ----
__global__ __launch_bounds__(256) void k_gemm1h(const float* __restrict__ xagg,
                                                const float* __restrict__ W1f,
                                                const float* __restrict__ b1f,
                                                float* __restrict__ h,
                                                float* __restrict__ nrm2, int N) {
    __shared__ float4 xs4[16][NFEAT / 4];   // 8 KB
    __shared__ float red[4][16];
    int i0 = blockIdx.x * 16;
    int tid = threadIdx.x;
    // stage 16 rows of xagg (float4 coalesced)
#pragma unroll
    for (int c = 0; c < 2; ++c) {
        int idx4 = c * 256 + tid;            // 512 float4s total
        int n = idx4 >> 5, kq = idx4 & 31;
        int i = i0 + n;
        float4 v = make_float4(0.f, 0.f, 0.f, 0.f);
        if (i < N) v = ((const float4*)(xagg + (size_t)i * NFEAT))[kq];
        xs4[n][kq] = v;
    }
    __syncthreads();
    int j = tid;
    float acc[16];
#pragma unroll
    for (int n = 0; n < 16; ++n) acc[n] = 0.f;
    for (int k = 0; k < NFEAT; k += 4) {
        float w0 = W1f[(size_t)(k + 0) * NHID + j];
        float w1 = W1f[(size_t)(k + 1) * NHID + j];
        float w2 = W1f[(size_t)(k + 2) * NHID + j];
        float w3 = W1f[(size_t)(k + 3) * NHID + j];
#pragma unroll
        for (int n = 0; n < 16; ++n) {
            float4 xv = xs4[n][k >> 2];
            acc[n] += xv.x * w0 + xv.y * w1 + xv.z * w2 + xv.w * w3;
        }
    }
    float bj = b1f[j];
    int w = tid >> 6, lane = tid & 63;
#pragma unroll
    for (int n = 0; n < 16; ++n) {
        int i = i0 + n;
        float v = fmaxf(acc[n] + bj, 0.0f);
        if (i < N) h[(size_t)i * NHID + j] = v;
        float s = waveSum(v * v);
        if (lane == 0) red[w][n] = s;
    }
    __syncthreads();
    if (tid < 16 && i0 + tid < N) {
        float s = red[0][tid] + red[1][tid] + red[2][tid] + red[3][tid];
        nrm2[i0 + tid] = fmaxf(sqrtf(s), FEPS);
    }
}

// ---- att2: 2 edges per wave, gated by mask1; 32 lanes x 2 float4 per row ----
__global__ void k_att2(const float* __restrict__ h,
                       const int* __restrict__ row, const int* __restrict__ col,
                       const float* __restrict__ nrm2, const float* __restrict__ w1,
                       float* __restrict__ w2e, float* __restrict__ deg, int E) {
    int wid = (blockIdx.x * blockDim.x + threadIdx.x) >> 6;
    int lane = threadIdx.x & 63;
    int half = lane >> 5, l32 = lane & 31;
    int e = wid * 2 + half;
    if (e >= E) return;
    float w1v = w1[e];
    if (w1v == 0.0f) { if (l32 == 0) w2e[e] = 0.0f; return; }
    int r = row[e], c = col[e];
    const float4* hr = (const float4*)(h + (size_t)r * NHID);
    const float4* hc = (const float4*)(h + (size_t)c * NHID);
    float4 a0 = hr[l32], a1 = hr[l32 + 32];
    float4 b0 = hc[l32], b1 = hc[l32 + 32];
    float s = halfSum(a0.x * b0.x + a0.y * b0.y + a0.z * b0.z + a0.w * b0.w +
                      a1.x * b1.x + a1.y * b1.y + a1.z * b1.z + a1.w * b1.w);
    if (l32 == 0) {
        float sims = s / (nrm2[r] * nrm2[c]);
        float w = (sims >= THRESH) ? sims : 0.0f;
        w2e[e] = w;
        if (w != 0.0f) unsafeAtomicAdd(&deg[r], w);
    }
}

// ---- gemm2 v2: g = h @ W2; 32 nodes/block; h tile in LDS as packed f16 ----
__global__ __launch_bounds__(256) void k_gemm2(const float* __restrict__ h,
                                               const float* __restrict__ W2f,
                                               float* __restrict__ g, int N) {
    __shared__ __half2 hs[32][NHID / 2 + 1];   // [32][129] u32 -> 16.5 KB
    __shared__ float w2s[NHID * NCLASS];       // 40 KB
    int tid = threadIdx.x;
    int i0 = blockIdx.x * 32;
    // stage W2
    for (int idx = tid; idx < NHID * NCLASS; idx += 256) w2s[idx] = W2f[idx];
    // stage h tile as f16 pairs (float2 coalesced reads)
#pragma unroll
    for (int c = 0; c < 16; ++c) {
        int p = c * 256 + tid;                 // 32 nodes * 128 pairs
        int n = p >> 7, kp = p & 127;
        int i = i0 + n;
        float2 hv = make_float2(0.f, 0.f);
        if (i < N) hv = ((const float2*)(h + (size_t)i * NHID))[kp];
        hs[n][kp] = __floats2half2_rn(hv.x, hv.y);
    }
    __syncthreads();
    int wv = tid >> 6;                          // wave -> class group of 10
    int lane = tid & 63;
    int n = lane & 31, half = lane >> 5;
    int j0 = wv * 10 + half * 5;                // 5 classes per thread
    int i = i0 + n;
    float acc[5] = {0.f, 0.f, 0.f, 0.f, 0.f};
    for (int kp = 0; kp < NHID / 2; ++kp) {
        float2 hf = __half22float2(hs[n][kp]);
        const float* wrow0 = w2s + (2 * kp) * NCLASS + j0;
        const float* wrow1 = w2s + (2 * kp + 1) * NCLASS + j0;
#pragma unroll
        for (int q = 0; q < 5; ++q)
            acc[q] += hf.x * wrow0[q] + hf.y * wrow1[q];
    }
    if (i < N) {
        float* gp = g + (size_t)i * NCLASS + j0;
#pragma unroll
        for (int q = 0; q < 5; ++q) gp[q] = acc[q];
    }
}

// ---- out init = dinv2^2 * g + b2 (full overwrite of poisoned d_out) ----
__global__ void k_selfout(const float* __restrict__ g, const float* __restrict__ dinv2,
                          const float* __restrict__ b2f, float* __restrict__ out, int n) {
    int idx = blockIdx.x * blockDim.x + threadIdx.x;
    if (idx >= n) return;
    int i = idx / NCLASS, j = idx - i * NCLASS;
    float d = dinv2[i];
    out[idx] = d * d * g[idx] + b2f[j];
}

// ---- scatter2: out[row] += norm * g[col] (wave per edge, 40 active lanes) ----
__global__ void k_scatter2(const float* __restrict__ g,
                           const int* __restrict__ row, const int* __restrict__ col,
                           const float* __restrict__ w2e, const float* __restrict__ dinv2,
                           float* __restrict__ out, int E) {
    int e = (blockIdx.x * blockDim.x + threadIdx.x) >> 6;
    int lane = threadIdx.x & 63;
    if (e >= E) return;
    float w = w2e[e];
    if (w == 0.0f || lane >= NCLASS) return;
    int r = row[e], c = col[e];
    float nm = dinv2[r] * w * dinv2[c];
    unsafeAtomicAdd(&out[(size_t)r * NCLASS + lane], nm * g[(size_t)c * NCLASS + lane]);
}

extern "C" void kernel_launch(void* const* d_in, const int* in_sizes, int n_in,
                              void* d_out, int out_size, void* d_ws, size_t ws_size,
                              hipStream_t stream) {
    const float* x  = (const float*)d_in[0];
    const int* row  = (const int*)d_in[1];
    const int* col  = (const int*)d_in[2];
    const float* W1 = (const float*)d_in[3];
    const float* b1 = (const float*)d_in[4];
    const float* W2 = (const float*)d_in[5];
    const float* b2 = (const float*)d_in[6];
    float* out = (float*)d_out;
    const int N = in_sizes[0] / NFEAT;
    const int E = in_sizes[1];

    // ---- workspace layout (~162.4 MB peak) ----
    char* ws = (char*)d_ws;
    size_t off = 0;
    auto alloc = [&](size_t bytes) {
        char* p = ws + off;
        off += (bytes + 255) & ~(size_t)255;
        return p;
    };
    float* xagg  = (float*)alloc((size_t)N * NFEAT * 4);   // 51.2 MB; g reuses after gemm1h
    float* h     = (float*)alloc((size_t)N * NHID * 4);    // 102.4 MB
    float* w1buf = (float*)alloc((size_t)E * 4);           // 4 MB
    float* w2buf = (float*)alloc((size_t)E * 4);           // 4 MB
    float* nrm   = (float*)alloc((size_t)N * 4);           // nrm1, later nrm2
    float* deg   = (float*)alloc((size_t)N * 4);           // degsum/dinv, both layers
    float* g     = xagg;                                   // 16 MB (xagg dead after gemm1h)

    const int e2Blocks = (int)(((size_t)E + 7) / 8);   // 2 edges/wave, 4 waves/block
    const int eBlocks  = (E + 3) / 4;                  // 1 edge/wave
    const int nBlocks4 = (N + 3) / 4;

    // ---- layer 1 ----
    hipMemsetAsync(deg, 0, (size_t)N * 4, stream);
    k_norm128<<<nBlocks4, 256, 0, stream>>>(x, nrm, N);
    k_att1<<<e2Blocks, 256, 0, stream>>>(x, row, col, nrm, w1buf, deg, E);
    k_dinv<<<(N + 255) / 256, 256, 0, stream>>>(deg, N);
    k_selfinit<<<(N * NFEAT + 255) / 256, 256, 0, stream>>>(x, deg, xagg, N * NFEAT);
    k_agg1<<<e2Blocks, 256, 0, stream>>>(x, row, col, w1buf, deg, xagg, E);
    k_gemm1h<<<(N + 15) / 16, 256, 0, stream>>>(xagg, W1, b1, h, nrm, N);

    // ---- layer 2 ----
    hipMemsetAsync(deg, 0, (size_t)N * 4, stream);
    k_att2<<<e2Blocks, 256, 0, stream>>>(h, row, col, nrm, w1buf, w2buf, deg, E);
    k_dinv<<<(N + 255) / 256, 256, 0, stream>>>(deg, N);
    k_gemm2<<<(N + 31) / 32, 256, 0, stream>>>(h, W2, g, N);
    k_selfout<<<(N * NCLASS + 255) / 256, 256, 0, stream>>>(g, deg, b2, out, N * NCLASS);
    k_scatter2<<<eBlocks, 256, 0, stream>>>(g, row, col, w2buf, deg, out, E);
}

// Round 5
// 694.170 us; speedup vs baseline: 1.6681x; 1.3347x over previous
//
#include <hip/hip_runtime.h>
#include <hip/hip_bf16.h>
#include <hip/hip_fp16.h>

#define NFEAT 128
#define NHID  256
#define NCLASS 40
#define THRESH 0.1f
#define FEPS   1e-8f

__device__ __forceinline__ float waveSum(float v) {
#pragma unroll
    for (int off = 32; off > 0; off >>= 1) v += __shfl_xor(v, off, 64);
    return v;
}

__device__ __forceinline__ float halfSum(float v) {
#pragma unroll
    for (int off = 16; off > 0; off >>= 1) v += __shfl_xor(v, off, 64);
    return v;
}

// ---- row norms, F=128 (wave per node, float2 per lane) ----
__global__ void k_norm128(const float* __restrict__ v, float* __restrict__ nrm, int N) {
    int wid = (blockIdx.x * blockDim.x + threadIdx.x) >> 6;
    int lane = threadIdx.x & 63;
    if (wid >= N) return;
    const float2* r = (const float2*)(v + (size_t)wid * NFEAT);
    float2 a = r[lane];
    float s = waveSum(a.x * a.x + a.y * a.y);
    if (lane == 0) nrm[wid] = fmaxf(sqrtf(s), FEPS);
}

// ---- att1: 2 edges/wave; w1 + float deg + int per-row count ----
__global__ void k_att1(const float* __restrict__ xf,
                       const int* __restrict__ row, const int* __restrict__ col,
                       const float* __restrict__ nrm,
                       float* __restrict__ w1, float* __restrict__ deg,
                       int* __restrict__ counts, int E) {
    int wid = (blockIdx.x * blockDim.x + threadIdx.x) >> 6;
    int lane = threadIdx.x & 63;
    int half = lane >> 5, l32 = lane & 31;
    int e = wid * 2 + half;
    if (e >= E) return;
    int r = row[e], c = col[e];
    float4 a = ((const float4*)(xf + (size_t)r * NFEAT))[l32];
    float4 b = ((const float4*)(xf + (size_t)c * NFEAT))[l32];
    float s = halfSum(a.x * b.x + a.y * b.y + a.z * b.z + a.w * b.w);
    if (l32 == 0) {
        float sims = s / (nrm[r] * nrm[c]);
        float w = (sims >= THRESH && r != c) ? sims : 0.0f;
        w1[e] = w;
        if (w != 0.0f) {
            unsafeAtomicAdd(&deg[r], w);
            atomicAdd(&counts[r], 1);
        }
    }
}

// ---- deg -> 1/sqrt(1+deg), in place ----
__global__ void k_dinv(float* __restrict__ d, int N) {
    int i = blockIdx.x * blockDim.x + threadIdx.x;
    if (i < N) d[i] = 1.0f / sqrtf(1.0f + d[i]);
}

// ---- exclusive scan of counts -> rowptr (3-kernel, N <= 512*256) ----
__global__ __launch_bounds__(256) void k_scan1(const int* __restrict__ counts,
                                               int* __restrict__ rowptr,
                                               int* __restrict__ bsum, int N) {
    __shared__ int tmp[256];
    int t = threadIdx.x, i = blockIdx.x * 256 + t;
    int v = (i < N) ? counts[i] : 0;
    tmp[t] = v;
    __syncthreads();
    for (int off = 1; off < 256; off <<= 1) {
        int add = (t >= off) ? tmp[t - off] : 0;
        __syncthreads();
        tmp[t] += add;
        __syncthreads();
    }
    if (i < N) rowptr[i] = tmp[t] - v;          // exclusive within block
    if (t == 255) bsum[blockIdx.x] = tmp[t];
}

__global__ __launch_bounds__(512) void k_scan2(int* __restrict__ bsum, int nb) {
    __shared__ int tmp[512];
    int t = threadIdx.x;
    int v = (t < nb) ? bsum[t] : 0;
    tmp[t] = v;
    __syncthreads();
    for (int off = 1; off < 512; off <<= 1) {
        int add = (t >= off) ? tmp[t - off] : 0;
        __syncthreads();
        tmp[t] += add;
        __syncthreads();
    }
    if (t < nb) bsum[t] = tmp[t] - v;           // exclusive block offsets
}

__global__ void k_scan3(int* __restrict__ rowptr, const int* __restrict__ bsum, int N) {
    int i = blockIdx.x * 256 + threadIdx.x;
    if (i < N) rowptr[i] += bsum[blockIdx.x];
}

// ---- fill CSR: edata[pos] = (col, norm); rowptr[r] advances to row end ----
__global__ void k_fill(const int* __restrict__ row, const int* __restrict__ col,
                       const float* __restrict__ wbuf, const float* __restrict__ dinv,
                       int* __restrict__ rowptr, int2* __restrict__ edata, int E) {
    int e = blockIdx.x * blockDim.x + threadIdx.x;
    if (e >= E) return;
    float w = wbuf[e];
    if (w == 0.0f) return;
    int r = row[e], c = col[e];
    float nm = dinv[r] * w * dinv[c];
    int pos = atomicAdd(&rowptr[r], 1);
    edata[pos] = make_int2(c, __float_as_int(nm));
}

// ---- gather1: xagg[r] = dinv[r]^2*x[r] + sum_e nm*x[c]  (wave per node) ----
__global__ void k_gather1(const float* __restrict__ xf, const int* __restrict__ rowptr,
                          const int* __restrict__ counts, const float* __restrict__ dinv,
                          const int2* __restrict__ edata, float* __restrict__ xagg, int N) {
    int r = (blockIdx.x * blockDim.x + threadIdx.x) >> 6;
    int lane = threadIdx.x & 63;
    if (r >= N) return;
    int cnt = counts[r];
    int start = rowptr[r] - cnt;                // fill advanced rowptr to end
    float d = dinv[r];
    float2 xa = ((const float2*)(xf + (size_t)r * NFEAT))[lane];
    float2 acc = make_float2(d * d * xa.x, d * d * xa.y);
    for (int k = 0; k < cnt; ++k) {
        int2 ed = edata[start + k];
        float nm = __int_as_float(ed.y);
        float2 xv = ((const float2*)(xf + (size_t)ed.x * NFEAT))[lane];
        acc.x += nm * xv.x;
        acc.y += nm * xv.y;
    }
    ((float2*)(xagg + (size_t)r * NFEAT))[lane] = acc;
}

// ---- h = relu(xagg @ W1 + b1), 16 nodes/block, fused row-norm of h ----
__global__ __launch_bounds__(256) void k_gemm1h(const float* __restrict__ xagg,
                                                const float* __restrict__ W1f,
                                                const float* __restrict__ b1f,
                                                float* __restrict__ h,
                                                float* __restrict__ nrm2, int N) {
    __shared__ float4 xs4[16][NFEAT / 4];   // 8 KB
    __shared__ float red[4][16];
    int i0 = blockIdx.x * 16;
    int tid = threadIdx.x;
#pragma unroll
    for (int c = 0; c < 2; ++c) {
        int idx4 = c * 256 + tid;
        int n = idx4 >> 5, kq = idx4 & 31;
        int i = i0 + n;
        float4 v = make_float4(0.f, 0.f, 0.f, 0.f);
        if (i < N) v = ((const float4*)(xagg + (size_t)i * NFEAT))[kq];
        xs4[n][kq] = v;
    }
    __syncthreads();
    int j = tid;
    float acc[16];
#pragma unroll
    for (int n = 0; n < 16; ++n) acc[n] = 0.f;
    for (int k = 0; k < NFEAT; k += 4) {
        float w0 = W1f[(size_t)(k + 0) * NHID + j];
        float w1 = W1f[(size_t)(k + 1) * NHID + j];
        float w2 = W1f[(size_t)(k + 2) * NHID + j];
        float w3 = W1f[(size_t)(k + 3) * NHID + j];
#pragma unroll
        for (int n = 0; n < 16; ++n) {
            float4 xv = xs4[n][k >> 2];
            acc[n] += xv.x * w0 + xv.y * w1 + xv.z * w2 + xv.w * w3;
        }
    }
    float bj = b1f[j];
    int w = tid >> 6, lane = tid & 63;
#pragma unroll
    for (int n = 0; n < 16; ++n) {
        int i = i0 + n;
        float v = fmaxf(acc[n] + bj, 0.0f);
        if (i < N) h[(size_t)i * NHID + j] = v;
        float s = waveSum(v * v);
        if (lane == 0) red[w][n] = s;
    }
    __syncthreads();
    if (tid < 16 && i0 + tid < N) {
        float s = red[0][tid] + red[1][tid] + red[2][tid] + red[3][tid];
        nrm2[i0 + tid] = fmaxf(sqrtf(s), FEPS);
    }
}

// ---- att2: 2 edges/wave, gated by mask1; w2 + deg + counts ----
__global__ void k_att2(const float* __restrict__ h,
                       const int* __restrict__ row, const int* __restrict__ col,
                       const float* __restrict__ nrm2, const float* __restrict__ w1,
                       float* __restrict__ w2e, float* __restrict__ deg,
                       int* __restrict__ counts, int E) {
    int wid = (blockIdx.x * blockDim.x + threadIdx.x) >> 6;
    int lane = threadIdx.x & 63;
    int half = lane >> 5, l32 = lane & 31;
    int e = wid * 2 + half;
    if (e >= E) return;
    float w1v = w1[e];
    if (w1v == 0.0f) { if (l32 == 0) w2e[e] = 0.0f; return; }
    int r = row[e], c = col[e];
    const float4* hr = (const float4*)(h + (size_t)r * NHID);
    const float4* hc = (const float4*)(h + (size_t)c * NHID);
    float4 a0 = hr[l32], a1 = hr[l32 + 32];
    float4 b0 = hc[l32], b1 = hc[l32 + 32];
    float s = halfSum(a0.x * b0.x + a0.y * b0.y + a0.z * b0.z + a0.w * b0.w +
                      a1.x * b1.x + a1.y * b1.y + a1.z * b1.z + a1.w * b1.w);
    if (l32 == 0) {
        float sims = s / (nrm2[r] * nrm2[c]);
        float w = (sims >= THRESH) ? sims : 0.0f;
        w2e[e] = w;
        if (w != 0.0f) {
            unsafeAtomicAdd(&deg[r], w);
            atomicAdd(&counts[r], 1);
        }
    }
}

// ---- gemm2: g = h @ W2; 32 nodes/block; h tile in LDS as packed f16 ----
__global__ __launch_bounds__(256) void k_gemm2(const float* __restrict__ h,
                                               const float* __restrict__ W2f,
                                               float* __restrict__ g, int N) {
    __shared__ __half2 hs[32][NHID / 2 + 1];   // 16.5 KB
    __shared__ float w2s[NHID * NCLASS];       // 40 KB
    int tid = threadIdx.x;
    int i0 = blockIdx.x * 32;
    for (int idx = tid; idx < NHID * NCLASS; idx += 256) w2s[idx] = W2f[idx];
#pragma unroll
    for (int c = 0; c < 16; ++c) {
        int p = c * 256 + tid;
        int n = p >> 7, kp = p & 127;
        int i = i0 + n;
        float2 hv = make_float2(0.f, 0.f);
        if (i < N) hv = ((const float2*)(h + (size_t)i * NHID))[kp];
        hs[n][kp] = __floats2half2_rn(hv.x, hv.y);
    }
    __syncthreads();
    int wv = tid >> 6;
    int lane = tid & 63;
    int n = lane & 31, half = lane >> 5;
    int j0 = wv * 10 + half * 5;
    int i = i0 + n;
    float acc[5] = {0.f, 0.f, 0.f, 0.f, 0.f};
    for (int kp = 0; kp < NHID / 2; ++kp) {
        float2 hf = __half22float2(hs[n][kp]);
        const float* wrow0 = w2s + (2 * kp) * NCLASS + j0;
        const float* wrow1 = w2s + (2 * kp + 1) * NCLASS + j0;
#pragma unroll
        for (int q = 0; q < 5; ++q)
            acc[q] += hf.x * wrow0[q] + hf.y * wrow1[q];
    }
    if (i < N) {
        float* gp = g + (size_t)i * NCLASS + j0;
#pragma unroll
        for (int q = 0; q < 5; ++q) gp[q] = acc[q];
    }
}

// ---- gather2: out[r] = dinv2^2*g[r] + b2 + sum_e nm*g[c]  (wave per node) ----
__global__ void k_gather2(const float* __restrict__ g, const int* __restrict__ rowptr,
                          const int* __restrict__ counts, const float* __restrict__ dinv2,
                          const float* __restrict__ b2f, const int2* __restrict__ edata,
                          float* __restrict__ out, int N) {
    int r = (blockIdx.x * blockDim.x + threadIdx.x) >> 6;
    int lane = threadIdx.x & 63;
    if (r >= N || lane >= NCLASS) return;
    int cnt = counts[r];
    int start = rowptr[r] - cnt;
    float d = dinv2[r];
    float acc = d * d * g[(size_t)r * NCLASS + lane] + b2f[lane];
    for (int k = 0; k < cnt; ++k) {
        int2 ed = edata[start + k];
        acc += __int_as_float(ed.y) * g[(size_t)ed.x * NCLASS + lane];
    }
    out[(size_t)r * NCLASS + lane] = acc;
}

extern "C" void kernel_launch(void* const* d_in, const int* in_sizes, int n_in,
                              void* d_out, int out_size, void* d_ws, size_t ws_size,
                              hipStream_t stream) {
    const float* x  = (const float*)d_in[0];
    const int* row  = (const int*)d_in[1];
    const int* col  = (const int*)d_in[2];
    const float* W1 = (const float*)d_in[3];
    const float* b1 = (const float*)d_in[4];
    const float* W2 = (const float*)d_in[5];
    const float* b2 = (const float*)d_in[6];
    float* out = (float*)d_out;
    const int N = in_sizes[0] / NFEAT;
    const int E = in_sizes[1];

    // ---- workspace layout (~171 MB peak) ----
    char* ws = (char*)d_ws;
    size_t off = 0;
    auto alloc = [&](size_t bytes) {
        char* p = ws + off;
        off += (bytes + 255) & ~(size_t)255;
        return p;
    };
    float* xagg   = (float*)alloc((size_t)N * NFEAT * 4);  // 51.2 MB; g reuses after gemm1h
    float* h      = (float*)alloc((size_t)N * NHID * 4);   // 102.4 MB
    float* w1buf  = (float*)alloc((size_t)E * 4);          // 4 MB
    float* w2buf  = (float*)alloc((size_t)E * 4);          // 4 MB
    int2*  edata  = (int2*)alloc((size_t)E * 8);           // 8 MB (compact CSR payload)
    float* nrm    = (float*)alloc((size_t)N * 4);
    float* deg    = (float*)alloc((size_t)N * 4);
    int*   counts = (int*)alloc((size_t)N * 4);
    int*   rowptr = (int*)alloc((size_t)N * 4);
    int*   bsum   = (int*)alloc(512 * 4);
    float* g      = xagg;                                  // xagg dead after gemm1h

    const int e2Blocks = (int)(((size_t)E + 7) / 8);   // 2 edges/wave
    const int eBlocks1 = (E + 255) / 256;              // 1 edge/thread
    const int nBlocks4 = (N + 3) / 4;                  // wave per node
    const int scanB    = (N + 255) / 256;              // 391 <= 512

    // ---- layer 1 ----
    hipMemsetAsync(deg, 0, (size_t)N * 4, stream);
    hipMemsetAsync(counts, 0, (size_t)N * 4, stream);
    k_norm128<<<nBlocks4, 256, 0, stream>>>(x, nrm, N);
    k_att1<<<e2Blocks, 256, 0, stream>>>(x, row, col, nrm, w1buf, deg, counts, E);
    k_dinv<<<(N + 255) / 256, 256, 0, stream>>>(deg, N);
    k_scan1<<<scanB, 256, 0, stream>>>(counts, rowptr, bsum, N);
    k_scan2<<<1, 512, 0, stream>>>(bsum, scanB);
    k_scan3<<<scanB, 256, 0, stream>>>(rowptr, bsum, N);
    k_fill<<<eBlocks1, 256, 0, stream>>>(row, col, w1buf, deg, rowptr, edata, E);
    k_gather1<<<nBlocks4, 256, 0, stream>>>(x, rowptr, counts, deg, edata, xagg, N);
    k_gemm1h<<<(N + 15) / 16, 256, 0, stream>>>(xagg, W1, b1, h, nrm, N);

    // ---- layer 2 ----
    hipMemsetAsync(deg, 0, (size_t)N * 4, stream);
    hipMemsetAsync(counts, 0, (size_t)N * 4, stream);
    k_att2<<<e2Blocks, 256, 0, stream>>>(h, row, col, nrm, w1buf, w2buf, deg, counts, E);
    k_dinv<<<(N + 255) / 256, 256, 0, stream>>>(deg, N);
    k_scan1<<<scanB, 256, 0, stream>>>(counts, rowptr, bsum, N);
    k_scan2<<<1, 512, 0, stream>>>(bsum, scanB);
    k_scan3<<<scanB, 256, 0, stream>>>(rowptr, bsum, N);
    k_fill<<<eBlocks1, 256, 0, stream>>>(row, col, w2buf, deg, rowptr, edata, E);
    k_gemm2<<<(N + 31) / 32, 256, 0, stream>>>(h, W2, g, N);
    k_gather2<<<nBlocks4, 256, 0, stream>>>(g, rowptr, counts, deg, b2, edata, out, N);
}

// Round 6
// 564.976 us; speedup vs baseline: 2.0496x; 1.2287x over previous
//
#include <hip/hip_runtime.h>
#include <hip/hip_bf16.h>
#include <hip/hip_fp16.h>

#define NFEAT 128
#define NHID  256
#define NCLASS 40
#define THRESH 0.1f
#define FEPS   1e-8f

__device__ __forceinline__ float waveSum(float v) {
#pragma unroll
    for (int off = 32; off > 0; off >>= 1) v += __shfl_xor(v, off, 64);
    return v;
}

__device__ __forceinline__ float halfSum(float v) {
#pragma unroll
    for (int off = 16; off > 0; off >>= 1) v += __shfl_xor(v, off, 64);
    return v;
}

// ---- row norms, F=128 (wave per node, float2 per lane) ----
__global__ void k_norm128(const float* __restrict__ v, float* __restrict__ nrm, int N) {
    int wid = (blockIdx.x * blockDim.x + threadIdx.x) >> 6;
    int lane = threadIdx.x & 63;
    if (wid >= N) return;
    const float2* r = (const float2*)(v + (size_t)wid * NFEAT);
    float2 a = r[lane];
    float s = waveSum(a.x * a.x + a.y * a.y);
    if (lane == 0) nrm[wid] = fmaxf(sqrtf(s), FEPS);
}

// ---- att1: 2 edges/wave; w1 + float deg + int per-row count ----
__global__ void k_att1(const float* __restrict__ xf,
                       const int* __restrict__ row, const int* __restrict__ col,
                       const float* __restrict__ nrm,
                       float* __restrict__ w1, float* __restrict__ deg,
                       int* __restrict__ counts, int E) {
    int wid = (blockIdx.x * blockDim.x + threadIdx.x) >> 6;
    int lane = threadIdx.x & 63;
    int half = lane >> 5, l32 = lane & 31;
    int e = wid * 2 + half;
    if (e >= E) return;
    int r = row[e], c = col[e];
    float4 a = ((const float4*)(xf + (size_t)r * NFEAT))[l32];
    float4 b = ((const float4*)(xf + (size_t)c * NFEAT))[l32];
    float s = halfSum(a.x * b.x + a.y * b.y + a.z * b.z + a.w * b.w);
    if (l32 == 0) {
        float sims = s / (nrm[r] * nrm[c]);
        float w = (sims >= THRESH && r != c) ? sims : 0.0f;
        w1[e] = w;
        if (w != 0.0f) {
            unsafeAtomicAdd(&deg[r], w);
            atomicAdd(&counts[r], 1);
        }
    }
}

// ---- deg -> 1/sqrt(1+deg), in place ----
__global__ void k_dinv(float* __restrict__ d, int N) {
    int i = blockIdx.x * blockDim.x + threadIdx.x;
    if (i < N) d[i] = 1.0f / sqrtf(1.0f + d[i]);
}

// ---- exclusive scan of counts -> rowptr (3-kernel, N <= 512*256) ----
__global__ __launch_bounds__(256) void k_scan1(const int* __restrict__ counts,
                                               int* __restrict__ rowptr,
                                               int* __restrict__ bsum, int N) {
    __shared__ int tmp[256];
    int t = threadIdx.x, i = blockIdx.x * 256 + t;
    int v = (i < N) ? counts[i] : 0;
    tmp[t] = v;
    __syncthreads();
    for (int off = 1; off < 256; off <<= 1) {
        int add = (t >= off) ? tmp[t - off] : 0;
        __syncthreads();
        tmp[t] += add;
        __syncthreads();
    }
    if (i < N) rowptr[i] = tmp[t] - v;
    if (t == 255) bsum[blockIdx.x] = tmp[t];
}

__global__ __launch_bounds__(512) void k_scan2(int* __restrict__ bsum, int nb) {
    __shared__ int tmp[512];
    int t = threadIdx.x;
    int v = (t < nb) ? bsum[t] : 0;
    tmp[t] = v;
    __syncthreads();
    for (int off = 1; off < 512; off <<= 1) {
        int add = (t >= off) ? tmp[t - off] : 0;
        __syncthreads();
        tmp[t] += add;
        __syncthreads();
    }
    if (t < nb) bsum[t] = tmp[t] - v;
}

__global__ void k_scan3(int* __restrict__ rowptr, const int* __restrict__ bsum, int N) {
    int i = blockIdx.x * 256 + threadIdx.x;
    if (i < N) rowptr[i] += bsum[blockIdx.x];
}

// ---- fill CSR: edata[pos] = (col, norm); rowptr[r] advances to row end ----
__global__ void k_fill(const int* __restrict__ row, const int* __restrict__ col,
                       const float* __restrict__ wbuf, const float* __restrict__ dinv,
                       int* __restrict__ rowptr, int2* __restrict__ edata, int E) {
    int e = blockIdx.x * blockDim.x + threadIdx.x;
    if (e >= E) return;
    float w = wbuf[e];
    if (w == 0.0f) return;
    int r = row[e], c = col[e];
    float nm = dinv[r] * w * dinv[c];
    int pos = atomicAdd(&rowptr[r], 1);
    edata[pos] = make_int2(c, __float_as_int(nm));
}

// ---- gather1: xagg[r] = dinv[r]^2*x[r] + sum_e nm*x[c]  (wave per node) ----
__global__ void k_gather1(const float* __restrict__ xf, const int* __restrict__ rowptr,
                          const int* __restrict__ counts, const float* __restrict__ dinv,
                          const int2* __restrict__ edata, float* __restrict__ xagg, int N) {
    int r = (blockIdx.x * blockDim.x + threadIdx.x) >> 6;
    int lane = threadIdx.x & 63;
    if (r >= N) return;
    int cnt = counts[r];
    int start = rowptr[r] - cnt;
    float d = dinv[r];
    float2 xa = ((const float2*)(xf + (size_t)r * NFEAT))[lane];
    float2 acc = make_float2(d * d * xa.x, d * d * xa.y);
    for (int k = 0; k < cnt; ++k) {
        int2 ed = edata[start + k];
        float nm = __int_as_float(ed.y);
        float2 xv = ((const float2*)(xf + (size_t)ed.x * NFEAT))[lane];
        acc.x += nm * xv.x;
        acc.y += nm * xv.y;
    }
    ((float2*)(xagg + (size_t)r * NFEAT))[lane] = acc;
}

// ---- gemm1h v3: h = relu(xagg @ W1 + b1), register-tiled; fused h row-norm ----
// block: 32 nodes x 256 cols; thread: 4 nodes x (4+4) cols
__global__ __launch_bounds__(256) void k_gemm1h(const float* __restrict__ xagg,
                                                const float* __restrict__ W1f,
                                                const float* __restrict__ b1f,
                                                float* __restrict__ h,
                                                float* __restrict__ nrm2, int N) {
    __shared__ float xT[NFEAT][36];     // transposed x tile, padded (18.4 KB)
    __shared__ float wsh[32][NHID];     // W1 k-chunk (32 KB)
    __shared__ float red[8][4];
    int tid = threadIdx.x;
    int i0 = blockIdx.x * 32;

    // stage xT: read 32 rows x 128 floats coalesced, scatter transposed
#pragma unroll
    for (int it = 0; it < 4; ++it) {
        int idx4 = it * 256 + tid;            // 1024 float4s
        int n = idx4 >> 5, kq = idx4 & 31;
        int i = i0 + n;
        float4 v = make_float4(0.f, 0.f, 0.f, 0.f);
        if (i < N) v = ((const float4*)(xagg + (size_t)i * NFEAT))[kq];
        xT[kq * 4 + 0][n] = v.x;
        xT[kq * 4 + 1][n] = v.y;
        xT[kq * 4 + 2][n] = v.z;
        xT[kq * 4 + 3][n] = v.w;
    }

    int lane = tid & 63, w = tid >> 6;
    int jg = lane & 31, ngl = lane >> 5;
    int ng = w * 2 + ngl;                     // node group 0..7
    int jA = jg * 4;                          // cols jA..+3 and 128+jA..+3

    float acc[4][8];
#pragma unroll
    for (int a = 0; a < 4; ++a)
#pragma unroll
        for (int b = 0; b < 8; ++b) acc[a][b] = 0.f;

    for (int kc = 0; kc < NFEAT; kc += 32) {
        __syncthreads();
        // stage W1 chunk [32][256]
#pragma unroll
        for (int it = 0; it < 8; ++it) {
            int idx4 = it * 256 + tid;        // 2048 float4s
            int kr = idx4 >> 6, jq = idx4 & 63;
            float4 v = ((const float4*)(W1f + (size_t)(kc + kr) * NHID))[jq];
            *((float4*)&wsh[kr][jq * 4]) = v;
        }
        __syncthreads();
#pragma unroll 4
        for (int kr = 0; kr < 32; ++kr) {
            float4 xv = *((const float4*)&xT[kc + kr][ng * 4]);
            float4 wa = *((const float4*)&wsh[kr][jA]);
            float4 wb = *((const float4*)&wsh[kr][128 + jA]);
            float xn[4] = {xv.x, xv.y, xv.z, xv.w};
            float wv[8] = {wa.x, wa.y, wa.z, wa.w, wb.x, wb.y, wb.z, wb.w};
#pragma unroll
            for (int a = 0; a < 4; ++a)
#pragma unroll
                for (int b = 0; b < 8; ++b) acc[a][b] += xn[a] * wv[b];
        }
    }

    float bA[8];
#pragma unroll
    for (int q = 0; q < 4; ++q) { bA[q] = b1f[jA + q]; bA[4 + q] = b1f[128 + jA + q]; }

#pragma unroll
    for (int a = 0; a < 4; ++a) {
        int i = i0 + ng * 4 + a;
        float4 va, vb;
        va.x = fmaxf(acc[a][0] + bA[0], 0.f);
        va.y = fmaxf(acc[a][1] + bA[1], 0.f);
        va.z = fmaxf(acc[a][2] + bA[2], 0.f);
        va.w = fmaxf(acc[a][3] + bA[3], 0.f);
        vb.x = fmaxf(acc[a][4] + bA[4], 0.f);
        vb.y = fmaxf(acc[a][5] + bA[5], 0.f);
        vb.z = fmaxf(acc[a][6] + bA[6], 0.f);
        vb.w = fmaxf(acc[a][7] + bA[7], 0.f);
        if (i < N) {
            *((float4*)(h + (size_t)i * NHID + jA)) = va;
            *((float4*)(h + (size_t)i * NHID + 128 + jA)) = vb;
        }
        float p = va.x * va.x + va.y * va.y + va.z * va.z + va.w * va.w +
                  vb.x * vb.x + vb.y * vb.y + vb.z * vb.z + vb.w * vb.w;
        p = halfSum(p);                      // sum over jg within 32-lane half
        if (jg == 0) red[ng][a] = p;
    }
    __syncthreads();
    if (tid < 32) {
        int i = i0 + tid;
        if (i < N) nrm2[i] = fmaxf(sqrtf(red[tid >> 2][tid & 3]), FEPS);
    }
}

// ---- att2 over layer-1 CSR: wave per row; writes w2csr + dinv2 (no atomics) ----
__global__ void k_att2csr(const float* __restrict__ h,
                          const int* __restrict__ rowptr, const int* __restrict__ counts,
                          const float* __restrict__ nrm2, const int2* __restrict__ edata,
                          float* __restrict__ w2csr, float* __restrict__ dinv2, int N) {
    int r = (blockIdx.x * blockDim.x + threadIdx.x) >> 6;
    int lane = threadIdx.x & 63;
    if (r >= N) return;
    int cnt = counts[r];
    int start = rowptr[r] - cnt;
    float deg = 0.f;
    if (cnt > 0) {
        float4 hr4 = ((const float4*)(h + (size_t)r * NHID))[lane];
        float nr = nrm2[r];
        for (int k = 0; k < cnt; ++k) {
            int c = edata[start + k].x;
            float4 hc4 = ((const float4*)(h + (size_t)c * NHID))[lane];
            float s = waveSum(hr4.x * hc4.x + hr4.y * hc4.y +
                              hr4.z * hc4.z + hr4.w * hc4.w);
            float sims = s / (nr * nrm2[c]);
            float w2 = (sims >= THRESH) ? sims : 0.f;
            if (lane == 0) w2csr[start + k] = w2;
            deg += w2;                       // wave-uniform after butterfly
        }
    }
    if (lane == 0) dinv2[r] = 1.0f / sqrtf(1.0f + deg);
}

// ---- gemm2: g = h @ W2; 32 nodes/block; h tile in LDS as packed f16 ----
__global__ __launch_bounds__(256) void k_gemm2(const float* __restrict__ h,
                                               const float* __restrict__ W2f,
                                               float* __restrict__ g, int N) {
    __shared__ __half2 hs[32][NHID / 2 + 1];   // 16.5 KB
    __shared__ float w2s[NHID * NCLASS];       // 40 KB
    int tid = threadIdx.x;
    int i0 = blockIdx.x * 32;
    for (int idx = tid; idx < NHID * NCLASS; idx += 256) w2s[idx] = W2f[idx];
#pragma unroll
    for (int c = 0; c < 16; ++c) {
        int p = c * 256 + tid;
        int n = p >> 7, kp = p & 127;
        int i = i0 + n;
        float2 hv = make_float2(0.f, 0.f);
        if (i < N) hv = ((const float2*)(h + (size_t)i * NHID))[kp];
        hs[n][kp] = __floats2half2_rn(hv.x, hv.y);
    }
    __syncthreads();
    int wv = tid >> 6;
    int lane = tid & 63;
    int n = lane & 31, half = lane >> 5;
    int j0 = wv * 10 + half * 5;
    int i = i0 + n;
    float acc[5] = {0.f, 0.f, 0.f, 0.f, 0.f};
    for (int kp = 0; kp < NHID / 2; ++kp) {
        float2 hf = __half22float2(hs[n][kp]);
        const float* wrow0 = w2s + (2 * kp) * NCLASS + j0;
        const float* wrow1 = w2s + (2 * kp + 1) * NCLASS + j0;
#pragma unroll
        for (int q = 0; q < 5; ++q)
            acc[q] += hf.x * wrow0[q] + hf.y * wrow1[q];
    }
    if (i < N) {
        float* gp = g + (size_t)i * NCLASS + j0;
#pragma unroll
        for (int q = 0; q < 5; ++q) gp[q] = acc[q];
    }
}

// ---- gather2: out[r] = dinv2^2*g[r] + b2 + sum_e dinv2[r]*w2*dinv2[c]*g[c] ----
__global__ void k_gather2(const float* __restrict__ g, const int* __restrict__ rowptr,
                          const int* __restrict__ counts, const float* __restrict__ dinv2,
                          const float* __restrict__ b2f, const int2* __restrict__ edata,
                          const float* __restrict__ w2csr, float* __restrict__ out, int N) {
    int r = (blockIdx.x * blockDim.x + threadIdx.x) >> 6;
    int lane = threadIdx.x & 63;
    if (r >= N || lane >= NCLASS) return;
    int cnt = counts[r];
    int start = rowptr[r] - cnt;
    float dr = dinv2[r];
    float acc = dr * dr * g[(size_t)r * NCLASS + lane] + b2f[lane];
    for (int k = 0; k < cnt; ++k) {
        int c = edata[start + k].x;
        float w2 = w2csr[start + k];
        acc += dr * w2 * dinv2[c] * g[(size_t)c * NCLASS + lane];
    }
    out[(size_t)r * NCLASS + lane] = acc;
}

extern "C" void kernel_launch(void* const* d_in, const int* in_sizes, int n_in,
                              void* d_out, int out_size, void* d_ws, size_t ws_size,
                              hipStream_t stream) {
    const float* x  = (const float*)d_in[0];
    const int* row  = (const int*)d_in[1];
    const int* col  = (const int*)d_in[2];
    const float* W1 = (const float*)d_in[3];
    const float* b1 = (const float*)d_in[4];
    const float* W2 = (const float*)d_in[5];
    const float* b2 = (const float*)d_in[6];
    float* out = (float*)d_out;
    const int N = in_sizes[0] / NFEAT;
    const int E = in_sizes[1];

    // ---- workspace layout (~171 MB peak) ----
    char* ws = (char*)d_ws;
    size_t off = 0;
    auto alloc = [&](size_t bytes) {
        char* p = ws + off;
        off += (bytes + 255) & ~(size_t)255;
        return p;
    };
    float* xagg   = (float*)alloc((size_t)N * NFEAT * 4);  // g reuses after gemm1h
    float* h      = (float*)alloc((size_t)N * NHID * 4);
    float* w1buf  = (float*)alloc((size_t)E * 4);
    float* w2csr  = (float*)alloc((size_t)E * 4);
    int2*  edata  = (int2*)alloc((size_t)E * 8);
    float* nrm    = (float*)alloc((size_t)N * 4);          // nrm1, then nrm2
    float* deg    = (float*)alloc((size_t)N * 4);          // deg1/dinv1
    float* dinv2  = (float*)alloc((size_t)N * 4);
    int*   counts = (int*)alloc((size_t)N * 4);
    int*   rowptr = (int*)alloc((size_t)N * 4);
    int*   bsum   = (int*)alloc(512 * 4);
    float* g      = xagg;

    const int e2Blocks = (int)(((size_t)E + 7) / 8);   // 2 edges/wave
    const int eBlocks1 = (E + 255) / 256;
    const int nBlocks4 = (N + 3) / 4;                  // wave per node
    const int scanB    = (N + 255) / 256;

    // ---- layer 1 ----
    hipMemsetAsync(deg, 0, (size_t)N * 4, stream);
    hipMemsetAsync(counts, 0, (size_t)N * 4, stream);
    k_norm128<<<nBlocks4, 256, 0, stream>>>(x, nrm, N);
    k_att1<<<e2Blocks, 256, 0, stream>>>(x, row, col, nrm, w1buf, deg, counts, E);
    k_dinv<<<(N + 255) / 256, 256, 0, stream>>>(deg, N);
    k_scan1<<<scanB, 256, 0, stream>>>(counts, rowptr, bsum, N);
    k_scan2<<<1, 512, 0, stream>>>(bsum, scanB);
    k_scan3<<<scanB, 256, 0, stream>>>(rowptr, bsum, N);
    k_fill<<<eBlocks1, 256, 0, stream>>>(row, col, w1buf, deg, rowptr, edata, E);
    k_gather1<<<nBlocks4, 256, 0, stream>>>(x, rowptr, counts, deg, edata, xagg, N);
    k_gemm1h<<<(N + 31) / 32, 256, 0, stream>>>(xagg, W1, b1, h, nrm, N);

    // ---- layer 2 (reuses layer-1 CSR; no atomics, no scan) ----
    k_att2csr<<<nBlocks4, 256, 0, stream>>>(h, rowptr, counts, nrm, edata, w2csr, dinv2, N);
    k_gemm2<<<(N + 31) / 32, 256, 0, stream>>>(h, W2, g, N);
    k_gather2<<<nBlocks4, 256, 0, stream>>>(g, rowptr, counts, dinv2, b2, edata, w2csr,
                                            out, N);
}

// Round 7
// 516.766 us; speedup vs baseline: 2.2408x; 1.0933x over previous
//
#include <hip/hip_runtime.h>
#include <hip/hip_bf16.h>
#include <hip/hip_fp16.h>

#define NFEAT 128
#define NHID  256
#define NCLASS 40
#define THRESH 0.1f
#define FEPS   1e-8f
#define GUARD  1e-3f

struct h2x2 { __half2 a, b; };   // 8-byte packed 4x fp16

__device__ __forceinline__ float waveSum(float v) {
#pragma unroll
    for (int off = 32; off > 0; off >>= 1) v += __shfl_xor(v, off, 64);
    return v;
}

__device__ __forceinline__ float halfSum(float v) {
#pragma unroll
    for (int off = 16; off > 0; off >>= 1) v += __shfl_xor(v, off, 64);
    return v;
}

// ---- prep: xh = fp16(x) + row norms (one read of x; wave per node) ----
__global__ void k_prep(const float* __restrict__ x, __half2* __restrict__ xh,
                       float* __restrict__ nrm, int N) {
    int r = (blockIdx.x * blockDim.x + threadIdx.x) >> 6;
    int lane = threadIdx.x & 63;
    if (r >= N) return;
    float2 a = ((const float2*)(x + (size_t)r * NFEAT))[lane];
    xh[(size_t)r * (NFEAT / 2) + lane] = __floats2half2_rn(a.x, a.y);
    float s = waveSum(a.x * a.x + a.y * a.y);
    if (lane == 0) nrm[r] = fmaxf(sqrtf(s), FEPS);
}

// ---- att1: 2 edges/wave over fp16 x; f32 guard-band recompute near threshold ----
__global__ void k_att1(const float* __restrict__ xf, const __half2* __restrict__ xh,
                       const int* __restrict__ row, const int* __restrict__ col,
                       const float* __restrict__ nrm,
                       float* __restrict__ w1, float* __restrict__ deg,
                       int* __restrict__ counts, int E) {
    int wid = (blockIdx.x * blockDim.x + threadIdx.x) >> 6;
    int lane = threadIdx.x & 63;
    int half = lane >> 5, l32 = lane & 31;
    int e = wid * 2 + half;
    if (e >= E) return;
    int r = row[e], c = col[e];
    // fp16 gather: 32 lanes x 2 half2 = 128 elements per row
    h2x2 av = ((const h2x2*)(xh + (size_t)r * (NFEAT / 2)))[l32];
    h2x2 bv = ((const h2x2*)(xh + (size_t)c * (NFEAT / 2)))[l32];
    float2 a0 = __half22float2(av.a), a1 = __half22float2(av.b);
    float2 b0 = __half22float2(bv.a), b1 = __half22float2(bv.b);
    float s = halfSum(a0.x * b0.x + a0.y * b0.y + a1.x * b1.x + a1.y * b1.y);
    float inv = 1.0f / (nrm[r] * nrm[c]);
    float sims = s * inv;
    if (__builtin_expect(fabsf(sims - THRESH) < GUARD, 0)) {
        // near the mask threshold: recompute exactly from f32 x
        float4 fa = ((const float4*)(xf + (size_t)r * NFEAT))[l32];
        float4 fb = ((const float4*)(xf + (size_t)c * NFEAT))[l32];
        float s2 = halfSum(fa.x * fb.x + fa.y * fb.y + fa.z * fb.z + fa.w * fb.w);
        sims = s2 * inv;
    }
    if (l32 == 0) {
        float w = (sims >= THRESH && r != c) ? sims : 0.0f;
        w1[e] = w;
        if (w != 0.0f) {
            unsafeAtomicAdd(&deg[r], w);
            atomicAdd(&counts[r], 1);
        }
    }
}

// ---- deg -> 1/sqrt(1+deg), in place ----
__global__ void k_dinv(float* __restrict__ d, int N) {
    int i = blockIdx.x * blockDim.x + threadIdx.x;
    if (i < N) d[i] = 1.0f / sqrtf(1.0f + d[i]);
}

// ---- exclusive scan of counts -> rowptr (3-kernel, N <= 512*256) ----
__global__ __launch_bounds__(256) void k_scan1(const int* __restrict__ counts,
                                               int* __restrict__ rowptr,
                                               int* __restrict__ bsum, int N) {
    __shared__ int tmp[256];
    int t = threadIdx.x, i = blockIdx.x * 256 + t;
    int v = (i < N) ? counts[i] : 0;
    tmp[t] = v;
    __syncthreads();
    for (int off = 1; off < 256; off <<= 1) {
        int add = (t >= off) ? tmp[t - off] : 0;
        __syncthreads();
        tmp[t] += add;
        __syncthreads();
    }
    if (i < N) rowptr[i] = tmp[t] - v;
    if (t == 255) bsum[blockIdx.x] = tmp[t];
}

__global__ __launch_bounds__(512) void k_scan2(int* __restrict__ bsum, int nb) {
    __shared__ int tmp[512];
    int t = threadIdx.x;
    int v = (t < nb) ? bsum[t] : 0;
    tmp[t] = v;
    __syncthreads();
    for (int off = 1; off < 512; off <<= 1) {
        int add = (t >= off) ? tmp[t - off] : 0;
        __syncthreads();
        tmp[t] += add;
        __syncthreads();
    }
    if (t < nb) bsum[t] = tmp[t] - v;
}

__global__ void k_scan3(int* __restrict__ rowptr, const int* __restrict__ bsum, int N) {
    int i = blockIdx.x * 256 + threadIdx.x;
    if (i < N) rowptr[i] += bsum[blockIdx.x];
}

// ---- fill CSR: edata[pos] = (col, norm); rowptr[r] advances to row end ----
__global__ void k_fill(const int* __restrict__ row, const int* __restrict__ col,
                       const float* __restrict__ wbuf, const float* __restrict__ dinv,
                       int* __restrict__ rowptr, int2* __restrict__ edata, int E) {
    int e = blockIdx.x * blockDim.x + threadIdx.x;
    if (e >= E) return;
    float w = wbuf[e];
    if (w == 0.0f) return;
    int r = row[e], c = col[e];
    float nm = dinv[r] * w * dinv[c];
    int pos = atomicAdd(&rowptr[r], 1);
    edata[pos] = make_int2(c, __float_as_int(nm));
}

// ---- gather1: xagg[r] = dinv[r]^2*x[r] + sum_e nm*x[c]  (wave per node, f32) ----
__global__ void k_gather1(const float* __restrict__ xf, const int* __restrict__ rowptr,
                          const int* __restrict__ counts, const float* __restrict__ dinv,
                          const int2* __restrict__ edata, float* __restrict__ xagg, int N) {
    int r = (blockIdx.x * blockDim.x + threadIdx.x) >> 6;
    int lane = threadIdx.x & 63;
    if (r >= N) return;
    int cnt = counts[r];
    int start = rowptr[r] - cnt;
    float d = dinv[r];
    float2 xa = ((const float2*)(xf + (size_t)r * NFEAT))[lane];
    float2 acc = make_float2(d * d * xa.x, d * d * xa.y);
    for (int k = 0; k < cnt; ++k) {
        int2 ed = edata[start + k];
        float nm = __int_as_float(ed.y);
        float2 xv = ((const float2*)(xf + (size_t)ed.x * NFEAT))[lane];
        acc.x += nm * xv.x;
        acc.y += nm * xv.y;
    }
    ((float2*)(xagg + (size_t)r * NFEAT))[lane] = acc;
}

// ---- gemm1h: h = relu(xagg @ W1 + b1), register-tiled; emits f32 h, fp16 hh, norms ----
__global__ __launch_bounds__(256) void k_gemm1h(const float* __restrict__ xagg,
                                                const float* __restrict__ W1f,
                                                const float* __restrict__ b1f,
                                                float* __restrict__ h,
                                                __half2* __restrict__ hh,
                                                float* __restrict__ nrm2, int N) {
    __shared__ float xT[NFEAT][36];     // transposed x tile, padded
    __shared__ float wsh[32][NHID];     // W1 k-chunk
    __shared__ float red[8][4];
    int tid = threadIdx.x;
    int i0 = blockIdx.x * 32;

#pragma unroll
    for (int it = 0; it < 4; ++it) {
        int idx4 = it * 256 + tid;
        int n = idx4 >> 5, kq = idx4 & 31;
        int i = i0 + n;
        float4 v = make_float4(0.f, 0.f, 0.f, 0.f);
        if (i < N) v = ((const float4*)(xagg + (size_t)i * NFEAT))[kq];
        xT[kq * 4 + 0][n] = v.x;
        xT[kq * 4 + 1][n] = v.y;
        xT[kq * 4 + 2][n] = v.z;
        xT[kq * 4 + 3][n] = v.w;
    }

    int lane = tid & 63, w = tid >> 6;
    int jg = lane & 31, ngl = lane >> 5;
    int ng = w * 2 + ngl;
    int jA = jg * 4;

    float acc[4][8];
#pragma unroll
    for (int a = 0; a < 4; ++a)
#pragma unroll
        for (int b = 0; b < 8; ++b) acc[a][b] = 0.f;

    for (int kc = 0; kc < NFEAT; kc += 32) {
        __syncthreads();
#pragma unroll
        for (int it = 0; it < 8; ++it) {
            int idx4 = it * 256 + tid;
            int kr = idx4 >> 6, jq = idx4 & 63;
            float4 v = ((const float4*)(W1f + (size_t)(kc + kr) * NHID))[jq];
            *((float4*)&wsh[kr][jq * 4]) = v;
        }
        __syncthreads();
#pragma unroll 4
        for (int kr = 0; kr < 32; ++kr) {
            float4 xv = *((const float4*)&xT[kc + kr][ng * 4]);
            float4 wa = *((const float4*)&wsh[kr][jA]);
            float4 wb = *((const float4*)&wsh[kr][128 + jA]);
            float xn[4] = {xv.x, xv.y, xv.z, xv.w};
            float wv[8] = {wa.x, wa.y, wa.z, wa.w, wb.x, wb.y, wb.z, wb.w};
#pragma unroll
            for (int a = 0; a < 4; ++a)
#pragma unroll
                for (int b = 0; b < 8; ++b) acc[a][b] += xn[a] * wv[b];
        }
    }

    float bA[8];
#pragma unroll
    for (int q = 0; q < 4; ++q) { bA[q] = b1f[jA + q]; bA[4 + q] = b1f[128 + jA + q]; }

#pragma unroll
    for (int a = 0; a < 4; ++a) {
        int i = i0 + ng * 4 + a;
        float4 va, vb;
        va.x = fmaxf(acc[a][0] + bA[0], 0.f);
        va.y = fmaxf(acc[a][1] + bA[1], 0.f);
        va.z = fmaxf(acc[a][2] + bA[2], 0.f);
        va.w = fmaxf(acc[a][3] + bA[3], 0.f);
        vb.x = fmaxf(acc[a][4] + bA[4], 0.f);
        vb.y = fmaxf(acc[a][5] + bA[5], 0.f);
        vb.z = fmaxf(acc[a][6] + bA[6], 0.f);
        vb.w = fmaxf(acc[a][7] + bA[7], 0.f);
        if (i < N) {
            *((float4*)(h + (size_t)i * NHID + jA)) = va;
            *((float4*)(h + (size_t)i * NHID + 128 + jA)) = vb;
            __half2* hhrow = hh + (size_t)i * (NHID / 2);
            h2x2 pa = { __floats2half2_rn(va.x, va.y), __floats2half2_rn(va.z, va.w) };
            h2x2 pb = { __floats2half2_rn(vb.x, vb.y), __floats2half2_rn(vb.z, vb.w) };
            ((h2x2*)hhrow)[jg] = pa;
            ((h2x2*)(hhrow + 64))[jg] = pb;
        }
        float p = va.x * va.x + va.y * va.y + va.z * va.z + va.w * va.w +
                  vb.x * vb.x + vb.y * vb.y + vb.z * vb.z + vb.w * vb.w;
        p = halfSum(p);
        if (jg == 0) red[ng][a] = p;
    }
    __syncthreads();
    if (tid < 32) {
        int i = i0 + tid;
        if (i < N) nrm2[i] = fmaxf(sqrtf(red[tid >> 2][tid & 3]), FEPS);
    }
}

// ---- att2 over CSR from fp16 h; f32 guard recompute; writes w2csr + dinv2 ----
__global__ void k_att2csr(const float* __restrict__ h, const __half2* __restrict__ hh,
                          const int* __restrict__ rowptr, const int* __restrict__ counts,
                          const float* __restrict__ nrm2, const int2* __restrict__ edata,
                          float* __restrict__ w2csr, float* __restrict__ dinv2, int N) {
    int r = (blockIdx.x * blockDim.x + threadIdx.x) >> 6;
    int lane = threadIdx.x & 63;
    if (r >= N) return;
    int cnt = counts[r];
    int start = rowptr[r] - cnt;
    float deg = 0.f;
    if (cnt > 0) {
        h2x2 hr = ((const h2x2*)(hh + (size_t)r * (NHID / 2)))[lane];
        float2 r0 = __half22float2(hr.a), r1 = __half22float2(hr.b);
        float nr = nrm2[r];
        for (int k = 0; k < cnt; ++k) {
            int c = edata[start + k].x;
            h2x2 hc = ((const h2x2*)(hh + (size_t)c * (NHID / 2)))[lane];
            float2 c0 = __half22float2(hc.a), c1 = __half22float2(hc.b);
            float s = waveSum(r0.x * c0.x + r0.y * c0.y + r1.x * c1.x + r1.y * c1.y);
            float inv = 1.0f / (nr * nrm2[c]);
            float sims = s * inv;
            if (__builtin_expect(fabsf(sims - THRESH) < GUARD, 0)) {
                float4 fr = ((const float4*)(h + (size_t)r * NHID))[lane];
                float4 fc = ((const float4*)(h + (size_t)c * NHID))[lane];
                float s2 = waveSum(fr.x * fc.x + fr.y * fc.y + fr.z * fc.z + fr.w * fc.w);
                sims = s2 * inv;
            }
            float w2 = (sims >= THRESH) ? sims : 0.f;
            if (lane == 0) w2csr[start + k] = w2;
            deg += w2;
        }
    }
    if (lane == 0) dinv2[r] = 1.0f / sqrtf(1.0f + deg);
}

// ---- gemm2: g = h @ W2; 32 nodes/block; stages fp16 h tile from hh ----
__global__ __launch_bounds__(256) void k_gemm2(const __half2* __restrict__ hh,
                                               const float* __restrict__ W2f,
                                               float* __restrict__ g, int N) {
    __shared__ __half2 hs[32][NHID / 2 + 1];   // [32][129]
    __shared__ float w2s[NHID * NCLASS];       // 40 KB
    int tid = threadIdx.x;
    int i0 = blockIdx.x * 32;
    for (int idx = tid; idx < NHID * NCLASS; idx += 256) w2s[idx] = W2f[idx];
#pragma unroll
    for (int c = 0; c < 8; ++c) {
        int p = c * 256 + tid;                 // 2048 h2x2 units
        int n = p >> 6, kp2 = (p & 63) * 2;
        int i = i0 + n;
        h2x2 v = { __floats2half2_rn(0.f, 0.f), __floats2half2_rn(0.f, 0.f) };
        if (i < N) v = ((const h2x2*)(hh + (size_t)i * (NHID / 2)))[p & 63];
        hs[n][kp2] = v.a;
        hs[n][kp2 + 1] = v.b;
    }
    __syncthreads();
    int wv = tid >> 6;
    int lane = tid & 63;
    int n = lane & 31, half = lane >> 5;
    int j0 = wv * 10 + half * 5;
    int i = i0 + n;
    float acc[5] = {0.f, 0.f, 0.f, 0.f, 0.f};
    for (int kp = 0; kp < NHID / 2; ++kp) {
        float2 hf = __half22float2(hs[n][kp]);
        const float* wrow0 = w2s + (2 * kp) * NCLASS + j0;
        const float* wrow1 = w2s + (2 * kp + 1) * NCLASS + j0;
#pragma unroll
        for (int q = 0; q < 5; ++q)
            acc[q] += hf.x * wrow0[q] + hf.y * wrow1[q];
    }
    if (i < N) {
        float* gp = g + (size_t)i * NCLASS + j0;
#pragma unroll
        for (int q = 0; q < 5; ++q) gp[q] = acc[q];
    }
}

// ---- gather2: out[r] = dinv2^2*g[r] + b2 + sum_e dinv2[r]*w2*dinv2[c]*g[c] ----
__global__ void k_gather2(const float* __restrict__ g, const int* __restrict__ rowptr,
                          const int* __restrict__ counts, const float* __restrict__ dinv2,
                          const float* __restrict__ b2f, const int2* __restrict__ edata,
                          const float* __restrict__ w2csr, float* __restrict__ out, int N) {
    int r = (blockIdx.x * blockDim.x + threadIdx.x) >> 6;
    int lane = threadIdx.x & 63;
    if (r >= N || lane >= NCLASS) return;
    int cnt = counts[r];
    int start = rowptr[r] - cnt;
    float dr = dinv2[r];
    float acc = dr * dr * g[(size_t)r * NCLASS + lane] + b2f[lane];
    for (int k = 0; k < cnt; ++k) {
        int c = edata[start + k].x;
        float w2 = w2csr[start + k];
        acc += dr * w2 * dinv2[c] * g[(size_t)c * NCLASS + lane];
    }
    out[(size_t)r * NCLASS + lane] = acc;
}

extern "C" void kernel_launch(void* const* d_in, const int* in_sizes, int n_in,
                              void* d_out, int out_size, void* d_ws, size_t ws_size,
                              hipStream_t stream) {
    const float* x  = (const float*)d_in[0];
    const int* row  = (const int*)d_in[1];
    const int* col  = (const int*)d_in[2];
    const float* W1 = (const float*)d_in[3];
    const float* b1 = (const float*)d_in[4];
    const float* W2 = (const float*)d_in[5];
    const float* b2 = (const float*)d_in[6];
    float* out = (float*)d_out;
    const int N = in_sizes[0] / NFEAT;
    const int E = in_sizes[1];

    // ---- workspace layout (~222 MB peak) ----
    char* ws = (char*)d_ws;
    size_t off = 0;
    auto alloc = [&](size_t bytes) {
        char* p = ws + off;
        off += (bytes + 255) & ~(size_t)255;
        return p;
    };
    float*   xagg   = (float*)alloc((size_t)N * NFEAT * 4);   // g reuses after gemm1h
    float*   h      = (float*)alloc((size_t)N * NHID * 4);
    __half2* hh     = (__half2*)alloc((size_t)N * NHID * 2);  // fp16 h mirror (51.2 MB)
    __half2* xh     = hh;                                     // fp16 x overlay (dead pre-gemm1h)
    float*   w1buf  = (float*)alloc((size_t)E * 4);
    float*   w2csr  = (float*)alloc((size_t)E * 4);
    int2*    edata  = (int2*)alloc((size_t)E * 8);
    float*   nrm    = (float*)alloc((size_t)N * 4);           // nrm1, then nrm2
    float*   deg    = (float*)alloc((size_t)N * 4);           // deg1/dinv1
    float*   dinv2  = (float*)alloc((size_t)N * 4);
    int*     counts = (int*)alloc((size_t)N * 4);
    int*     rowptr = (int*)alloc((size_t)N * 4);
    int*     bsum   = (int*)alloc(512 * 4);
    float*   g      = xagg;

    const int e2Blocks = (int)(((size_t)E + 7) / 8);
    const int eBlocks1 = (E + 255) / 256;
    const int nBlocks4 = (N + 3) / 4;
    const int scanB    = (N + 255) / 256;

    // ---- layer 1 ----
    hipMemsetAsync(deg, 0, (size_t)N * 4, stream);
    hipMemsetAsync(counts, 0, (size_t)N * 4, stream);
    k_prep<<<nBlocks4, 256, 0, stream>>>(x, xh, nrm, N);
    k_att1<<<e2Blocks, 256, 0, stream>>>(x, xh, row, col, nrm, w1buf, deg, counts, E);
    k_dinv<<<(N + 255) / 256, 256, 0, stream>>>(deg, N);
    k_scan1<<<scanB, 256, 0, stream>>>(counts, rowptr, bsum, N);
    k_scan2<<<1, 512, 0, stream>>>(bsum, scanB);
    k_scan3<<<scanB, 256, 0, stream>>>(rowptr, bsum, N);
    k_fill<<<eBlocks1, 256, 0, stream>>>(row, col, w1buf, deg, rowptr, edata, E);
    k_gather1<<<nBlocks4, 256, 0, stream>>>(x, rowptr, counts, deg, edata, xagg, N);
    k_gemm1h<<<(N + 31) / 32, 256, 0, stream>>>(xagg, W1, b1, h, hh, nrm, N);

    // ---- layer 2 (reuses layer-1 CSR; fp16 h gathers) ----
    k_att2csr<<<nBlocks4, 256, 0, stream>>>(h, hh, rowptr, counts, nrm, edata,
                                            w2csr, dinv2, N);
    k_gemm2<<<(N + 31) / 32, 256, 0, stream>>>(hh, W2, g, N);
    k_gather2<<<nBlocks4, 256, 0, stream>>>(g, rowptr, counts, dinv2, b2, edata, w2csr,
                                            out, N);
}

// Round 8
// 474.297 us; speedup vs baseline: 2.4414x; 1.0895x over previous
//
#include <hip/hip_runtime.h>
#include <hip/hip_bf16.h>
#include <hip/hip_fp16.h>

#define NFEAT 128
#define NHID  256
#define NCLASS 40
#define THRESH 0.1f
#define FEPS   1e-8f
#define GUARD  1e-3f

struct h2x2 { __half2 a, b; };   // 8-byte packed 4x fp16

typedef _Float16 v2h __attribute__((ext_vector_type(2)));

// fdot2: s += dot(2xfp16, 2xfp16) in one VALU op where available
__device__ __forceinline__ float dot2acc(unsigned int a, unsigned int b, float s) {
#if __has_builtin(__builtin_amdgcn_fdot2)
    return __builtin_amdgcn_fdot2(__builtin_bit_cast(v2h, a),
                                  __builtin_bit_cast(v2h, b), s, false);
#else
    float2 fa = __half22float2(__builtin_bit_cast(__half2, a));
    float2 fb = __half22float2(__builtin_bit_cast(__half2, b));
    return s + fa.x * fb.x + fa.y * fb.y;
#endif
}

__device__ __forceinline__ float waveSum(float v) {
#pragma unroll
    for (int off = 32; off > 0; off >>= 1) v += __shfl_xor(v, off, 64);
    return v;
}

__device__ __forceinline__ float halfSum(float v) {
#pragma unroll
    for (int off = 16; off > 0; off >>= 1) v += __shfl_xor(v, off, 64);
    return v;
}

__device__ __forceinline__ float qSum16(float v) {
#pragma unroll
    for (int off = 8; off > 0; off >>= 1) v += __shfl_xor(v, off, 64);
    return v;
}

// ---- prep: nrm + normalized fp16 xn + zero-init deg/counts (wave per node) ----
__global__ void k_prep(const float* __restrict__ x, __half2* __restrict__ xn,
                       float* __restrict__ nrm, float* __restrict__ deg,
                       int* __restrict__ counts, int N) {
    int r = (blockIdx.x * blockDim.x + threadIdx.x) >> 6;
    int lane = threadIdx.x & 63;
    if (r >= N) return;
    float2 a = ((const float2*)(x + (size_t)r * NFEAT))[lane];
    float s = waveSum(a.x * a.x + a.y * a.y);        // butterfly: all lanes get sum
    float nr = fmaxf(sqrtf(s), FEPS);
    float inv = 1.0f / nr;
    xn[(size_t)r * (NFEAT / 2) + lane] = __floats2half2_rn(a.x * inv, a.y * inv);
    if (lane == 0) {
        nrm[r] = nr;
        deg[r] = 0.0f;
        counts[r] = 0;
    }
}

// ---- att1: 4 edges/wave (16-lane groups) over normalized fp16 x; fdot2 ----
__global__ void k_att1(const float* __restrict__ xf, const __half2* __restrict__ xn,
                       const int* __restrict__ row, const int* __restrict__ col,
                       const float* __restrict__ nrm,
                       float* __restrict__ w1, float* __restrict__ deg,
                       int* __restrict__ counts, int E) {
    int wid = (blockIdx.x * blockDim.x + threadIdx.x) >> 6;
    int lane = threadIdx.x & 63;
    int g = lane >> 4, l16 = lane & 15;
    int e = wid * 4 + g;
    if (e >= E) return;
    int r = row[e], c = col[e];
    // one 16B load per row per lane: 16 lanes x 16 B = 256 B row
    uint4 av = ((const uint4*)(xn + (size_t)r * (NFEAT / 2)))[l16];
    uint4 bv = ((const uint4*)(xn + (size_t)c * (NFEAT / 2)))[l16];
    float s = 0.f;
    s = dot2acc(av.x, bv.x, s);
    s = dot2acc(av.y, bv.y, s);
    s = dot2acc(av.z, bv.z, s);
    s = dot2acc(av.w, bv.w, s);
    float sims = qSum16(s);
    if (__builtin_expect(fabsf(sims - THRESH) < GUARD, 0)) {
        // near threshold: recompute exactly from f32 x
        const float4* fr = (const float4*)(xf + (size_t)r * NFEAT);
        const float4* fc = (const float4*)(xf + (size_t)c * NFEAT);
        float4 a0 = fr[l16], a1 = fr[l16 + 16];
        float4 b0 = fc[l16], b1 = fc[l16 + 16];
        float s2 = qSum16(a0.x * b0.x + a0.y * b0.y + a0.z * b0.z + a0.w * b0.w +
                          a1.x * b1.x + a1.y * b1.y + a1.z * b1.z + a1.w * b1.w);
        sims = s2 / (nrm[r] * nrm[c]);
    }
    if (l16 == 0) {
        float w = (sims >= THRESH && r != c) ? sims : 0.0f;
        w1[e] = w;
        if (w != 0.0f) {
            unsafeAtomicAdd(&deg[r], w);
            atomicAdd(&counts[r], 1);
        }
    }
}

// ---- exclusive scan of counts -> rowptr (3-kernel, N <= 512*256) ----
__global__ __launch_bounds__(256) void k_scan1(const int* __restrict__ counts,
                                               int* __restrict__ rowptr,
                                               int* __restrict__ bsum, int N) {
    __shared__ int tmp[256];
    int t = threadIdx.x, i = blockIdx.x * 256 + t;
    int v = (i < N) ? counts[i] : 0;
    tmp[t] = v;
    __syncthreads();
    for (int off = 1; off < 256; off <<= 1) {
        int add = (t >= off) ? tmp[t - off] : 0;
        __syncthreads();
        tmp[t] += add;
        __syncthreads();
    }
    if (i < N) rowptr[i] = tmp[t] - v;
    if (t == 255) bsum[blockIdx.x] = tmp[t];
}

__global__ __launch_bounds__(512) void k_scan2(int* __restrict__ bsum, int nb) {
    __shared__ int tmp[512];
    int t = threadIdx.x;
    int v = (t < nb) ? bsum[t] : 0;
    tmp[t] = v;
    __syncthreads();
    for (int off = 1; off < 512; off <<= 1) {
        int add = (t >= off) ? tmp[t - off] : 0;
        __syncthreads();
        tmp[t] += add;
        __syncthreads();
    }
    if (t < nb) bsum[t] = tmp[t] - v;
}

__global__ void k_scan3(int* __restrict__ rowptr, const int* __restrict__ bsum, int N) {
    int i = blockIdx.x * 256 + threadIdx.x;
    if (i < N) rowptr[i] += bsum[blockIdx.x];
}

// ---- fill CSR: edata[pos] = (col, norm); dinv computed inline from deg ----
__global__ void k_fill(const int* __restrict__ row, const int* __restrict__ col,
                       const float* __restrict__ wbuf, const float* __restrict__ deg,
                       int* __restrict__ rowptr, int2* __restrict__ edata, int E) {
    int e = blockIdx.x * blockDim.x + threadIdx.x;
    if (e >= E) return;
    float w = wbuf[e];
    if (w == 0.0f) return;
    int r = row[e], c = col[e];
    float dr = 1.0f / sqrtf(1.0f + deg[r]);
    float dc = 1.0f / sqrtf(1.0f + deg[c]);
    float nm = dr * w * dc;
    int pos = atomicAdd(&rowptr[r], 1);
    edata[pos] = make_int2(c, __float_as_int(nm));
}

// ---- gather1: xagg[r] = dinv^2*x[r] + sum_e nm*x[c]  (wave per node, f32) ----
__global__ void k_gather1(const float* __restrict__ xf, const int* __restrict__ rowptr,
                          const int* __restrict__ counts, const float* __restrict__ deg,
                          const int2* __restrict__ edata, float* __restrict__ xagg, int N) {
    int r = (blockIdx.x * blockDim.x + threadIdx.x) >> 6;
    int lane = threadIdx.x & 63;
    if (r >= N) return;
    int cnt = counts[r];
    int start = rowptr[r] - cnt;
    float d = 1.0f / sqrtf(1.0f + deg[r]);
    float2 xa = ((const float2*)(xf + (size_t)r * NFEAT))[lane];
    float2 acc = make_float2(d * d * xa.x, d * d * xa.y);
    for (int k = 0; k < cnt; ++k) {
        int2 ed = edata[start + k];
        float nm = __int_as_float(ed.y);
        float2 xv = ((const float2*)(xf + (size_t)ed.x * NFEAT))[lane];
        acc.x += nm * xv.x;
        acc.y += nm * xv.y;
    }
    ((float2*)(xagg + (size_t)r * NFEAT))[lane] = acc;
}

// ---- gemm1h: h = relu(xagg @ W1 + b1), register-tiled; emits f32 h, fp16 hh, norms ----
__global__ __launch_bounds__(256) void k_gemm1h(const float* __restrict__ xagg,
                                                const float* __restrict__ W1f,
                                                const float* __restrict__ b1f,
                                                float* __restrict__ h,
                                                __half2* __restrict__ hh,
                                                float* __restrict__ nrm2, int N) {
    __shared__ float xT[NFEAT][36];     // transposed x tile, padded
    __shared__ float wsh[32][NHID];     // W1 k-chunk
    __shared__ float red[8][4];
    int tid = threadIdx.x;
    int i0 = blockIdx.x * 32;

#pragma unroll
    for (int it = 0; it < 4; ++it) {
        int idx4 = it * 256 + tid;
        int n = idx4 >> 5, kq = idx4 & 31;
        int i = i0 + n;
        float4 v = make_float4(0.f, 0.f, 0.f, 0.f);
        if (i < N) v = ((const float4*)(xagg + (size_t)i * NFEAT))[kq];
        xT[kq * 4 + 0][n] = v.x;
        xT[kq * 4 + 1][n] = v.y;
        xT[kq * 4 + 2][n] = v.z;
        xT[kq * 4 + 3][n] = v.w;
    }

    int lane = tid & 63, w = tid >> 6;
    int jg = lane & 31, ngl = lane >> 5;
    int ng = w * 2 + ngl;
    int jA = jg * 4;

    float acc[4][8];
#pragma unroll
    for (int a = 0; a < 4; ++a)
#pragma unroll
        for (int b = 0; b < 8; ++b) acc[a][b] = 0.f;

    for (int kc = 0; kc < NFEAT; kc += 32) {
        __syncthreads();
#pragma unroll
        for (int it = 0; it < 8; ++it) {
            int idx4 = it * 256 + tid;
            int kr = idx4 >> 6, jq = idx4 & 63;
            float4 v = ((const float4*)(W1f + (size_t)(kc + kr) * NHID))[jq];
            *((float4*)&wsh[kr][jq * 4]) = v;
        }
        __syncthreads();
#pragma unroll 4
        for (int kr = 0; kr < 32; ++kr) {
            float4 xv = *((const float4*)&xT[kc + kr][ng * 4]);
            float4 wa = *((const float4*)&wsh[kr][jA]);
            float4 wb = *((const float4*)&wsh[kr][128 + jA]);
            float xnv[4] = {xv.x, xv.y, xv.z, xv.w};
            float wv[8] = {wa.x, wa.y, wa.z, wa.w, wb.x, wb.y, wb.z, wb.w};
#pragma unroll
            for (int a = 0; a < 4; ++a)
#pragma unroll
                for (int b = 0; b < 8; ++b) acc[a][b] += xnv[a] * wv[b];
        }
    }

    float bA[8];
#pragma unroll
    for (int q = 0; q < 4; ++q) { bA[q] = b1f[jA + q]; bA[4 + q] = b1f[128 + jA + q]; }

#pragma unroll
    for (int a = 0; a < 4; ++a) {
        int i = i0 + ng * 4 + a;
        float4 va, vb;
        va.x = fmaxf(acc[a][0] + bA[0], 0.f);
        va.y = fmaxf(acc[a][1] + bA[1], 0.f);
        va.z = fmaxf(acc[a][2] + bA[2], 0.f);
        va.w = fmaxf(acc[a][3] + bA[3], 0.f);
        vb.x = fmaxf(acc[a][4] + bA[4], 0.f);
        vb.y = fmaxf(acc[a][5] + bA[5], 0.f);
        vb.z = fmaxf(acc[a][6] + bA[6], 0.f);
        vb.w = fmaxf(acc[a][7] + bA[7], 0.f);
        if (i < N) {
            *((float4*)(h + (size_t)i * NHID + jA)) = va;
            *((float4*)(h + (size_t)i * NHID + 128 + jA)) = vb;
            __half2* hhrow = hh + (size_t)i * (NHID / 2);
            h2x2 pa = { __floats2half2_rn(va.x, va.y), __floats2half2_rn(va.z, va.w) };
            h2x2 pb = { __floats2half2_rn(vb.x, vb.y), __floats2half2_rn(vb.z, vb.w) };
            ((h2x2*)hhrow)[jg] = pa;
            ((h2x2*)(hhrow + 64))[jg] = pb;
        }
        float p = va.x * va.x + va.y * va.y + va.z * va.z + va.w * va.w +
                  vb.x * vb.x + vb.y * vb.y + vb.z * vb.z + vb.w * vb.w;
        p = halfSum(p);
        if (jg == 0) red[ng][a] = p;
    }
    __syncthreads();
    if (tid < 32) {
        int i = i0 + tid;
        if (i < N) nrm2[i] = fmaxf(sqrtf(red[tid >> 2][tid & 3]), FEPS);
    }
}

// ---- att2 over CSR from fp16 h (fdot2); f32 guard recompute; w2csr + dinv2 ----
__global__ void k_att2csr(const float* __restrict__ h, const __half2* __restrict__ hh,
                          const int* __restrict__ rowptr, const int* __restrict__ counts,
                          const float* __restrict__ nrm2, const int2* __restrict__ edata,
                          float* __restrict__ w2csr, float* __restrict__ dinv2, int N) {
    int r = (blockIdx.x * blockDim.x + threadIdx.x) >> 6;
    int lane = threadIdx.x & 63;
    if (r >= N) return;
    int cnt = counts[r];
    int start = rowptr[r] - cnt;
    float deg = 0.f;
    if (cnt > 0) {
        uint2 hr = ((const uint2*)(hh + (size_t)r * (NHID / 2)))[lane];
        float nr = nrm2[r];
        for (int k = 0; k < cnt; ++k) {
            int c = edata[start + k].x;
            uint2 hc = ((const uint2*)(hh + (size_t)c * (NHID / 2)))[lane];
            float s = dot2acc(hr.y, hc.y, dot2acc(hr.x, hc.x, 0.f));
            s = waveSum(s);
            float inv = 1.0f / (nr * nrm2[c]);
            float sims = s * inv;
            if (__builtin_expect(fabsf(sims - THRESH) < GUARD, 0)) {
                float4 fr = ((const float4*)(h + (size_t)r * NHID))[lane];
                float4 fc = ((const float4*)(h + (size_t)c * NHID))[lane];
                float s2 = waveSum(fr.x * fc.x + fr.y * fc.y + fr.z * fc.z + fr.w * fc.w);
                sims = s2 * inv;
            }
            float w2 = (sims >= THRESH) ? sims : 0.f;
            if (lane == 0) w2csr[start + k] = w2;
            deg += w2;
        }
    }
    if (lane == 0) dinv2[r] = 1.0f / sqrtf(1.0f + deg);
}

// ---- gemm2: g = h @ W2; 32 nodes/block; stages fp16 h tile from hh ----
__global__ __launch_bounds__(256) void k_gemm2(const __half2* __restrict__ hh,
                                               const float* __restrict__ W2f,
                                               float* __restrict__ g, int N) {
    __shared__ __half2 hs[32][NHID / 2 + 1];   // [32][129]
    __shared__ float w2s[NHID * NCLASS];       // 40 KB
    int tid = threadIdx.x;
    int i0 = blockIdx.x * 32;
    for (int idx = tid; idx < NHID * NCLASS; idx += 256) w2s[idx] = W2f[idx];
#pragma unroll
    for (int c = 0; c < 8; ++c) {
        int p = c * 256 + tid;                 // 2048 h2x2 units
        int n = p >> 6, kp2 = (p & 63) * 2;
        int i = i0 + n;
        h2x2 v = { __floats2half2_rn(0.f, 0.f), __floats2half2_rn(0.f, 0.f) };
        if (i < N) v = ((const h2x2*)(hh + (size_t)i * (NHID / 2)))[p & 63];
        hs[n][kp2] = v.a;
        hs[n][kp2 + 1] = v.b;
    }
    __syncthreads();
    int wv = tid >> 6;
    int lane = tid & 63;
    int n = lane & 31, half = lane >> 5;
    int j0 = wv * 10 + half * 5;
    int i = i0 + n;
    float acc[5] = {0.f, 0.f, 0.f, 0.f, 0.f};
    for (int kp = 0; kp < NHID / 2; ++kp) {
        float2 hf = __half22float2(hs[n][kp]);
        const float* wrow0 = w2s + (2 * kp) * NCLASS + j0;
        const float* wrow1 = w2s + (2 * kp + 1) * NCLASS + j0;
#pragma unroll
        for (int q = 0; q < 5; ++q)
            acc[q] += hf.x * wrow0[q] + hf.y * wrow1[q];
    }
    if (i < N) {
        float* gp = g + (size_t)i * NCLASS + j0;
#pragma unroll
        for (int q = 0; q < 5; ++q) gp[q] = acc[q];
    }
}

// ---- gather2: out[r] = dinv2^2*g[r] + b2 + sum_e dinv2[r]*w2*dinv2[c]*g[c] ----
__global__ void k_gather2(const float* __restrict__ g, const int* __restrict__ rowptr,
                          const int* __restrict__ counts, const float* __restrict__ dinv2,
                          const float* __restrict__ b2f, const int2* __restrict__ edata,
                          const float* __restrict__ w2csr, float* __restrict__ out, int N) {
    int r = (blockIdx.x * blockDim.x + threadIdx.x) >> 6;
    int lane = threadIdx.x & 63;
    if (r >= N || lane >= NCLASS) return;
    int cnt = counts[r];
    int start = rowptr[r] - cnt;
    float dr = dinv2[r];
    float acc = dr * dr * g[(size_t)r * NCLASS + lane] + b2f[lane];
    for (int k = 0; k < cnt; ++k) {
        int c = edata[start + k].x;
        float w2 = w2csr[start + k];
        acc += dr * w2 * dinv2[c] * g[(size_t)c * NCLASS + lane];
    }
    out[(size_t)r * NCLASS + lane] = acc;
}

extern "C" void kernel_launch(void* const* d_in, const int* in_sizes, int n_in,
                              void* d_out, int out_size, void* d_ws, size_t ws_size,
                              hipStream_t stream) {
    const float* x  = (const float*)d_in[0];
    const int* row  = (const int*)d_in[1];
    const int* col  = (const int*)d_in[2];
    const float* W1 = (const float*)d_in[3];
    const float* b1 = (const float*)d_in[4];
    const float* W2 = (const float*)d_in[5];
    const float* b2 = (const float*)d_in[6];
    float* out = (float*)d_out;
    const int N = in_sizes[0] / NFEAT;
    const int E = in_sizes[1];

    // ---- workspace layout (~222 MB peak) ----
    char* ws = (char*)d_ws;
    size_t off = 0;
    auto alloc = [&](size_t bytes) {
        char* p = ws + off;
        off += (bytes + 255) & ~(size_t)255;
        return p;
    };
    float*   xagg   = (float*)alloc((size_t)N * NFEAT * 4);   // g reuses after gemm1h
    float*   h      = (float*)alloc((size_t)N * NHID * 4);
    __half2* hh     = (__half2*)alloc((size_t)N * NHID * 2);  // fp16 h mirror
    __half2* xn     = hh;                                     // normalized fp16 x overlay
    float*   w1buf  = (float*)alloc((size_t)E * 4);
    float*   w2csr  = (float*)alloc((size_t)E * 4);
    int2*    edata  = (int2*)alloc((size_t)E * 8);
    float*   nrm    = (float*)alloc((size_t)N * 4);           // nrm1, then nrm2
    float*   deg    = (float*)alloc((size_t)N * 4);           // degsum layer 1
    float*   dinv2  = (float*)alloc((size_t)N * 4);
    int*     counts = (int*)alloc((size_t)N * 4);
    int*     rowptr = (int*)alloc((size_t)N * 4);
    int*     bsum   = (int*)alloc(512 * 4);
    float*   g      = xagg;

    const int e4Blocks = (E + 15) / 16;   // 4 edges/wave, 4 waves/block
    const int eBlocks1 = (E + 255) / 256;
    const int nBlocks4 = (N + 3) / 4;
    const int scanB    = (N + 255) / 256;

    // ---- layer 1 ----
    k_prep<<<nBlocks4, 256, 0, stream>>>(x, xn, nrm, deg, counts, N);
    k_att1<<<e4Blocks, 256, 0, stream>>>(x, xn, row, col, nrm, w1buf, deg, counts, E);
    k_scan1<<<scanB, 256, 0, stream>>>(counts, rowptr, bsum, N);
    k_scan2<<<1, 512, 0, stream>>>(bsum, scanB);
    k_scan3<<<scanB, 256, 0, stream>>>(rowptr, bsum, N);
    k_fill<<<eBlocks1, 256, 0, stream>>>(row, col, w1buf, deg, rowptr, edata, E);
    k_gather1<<<nBlocks4, 256, 0, stream>>>(x, rowptr, counts, deg, edata, xagg, N);
    k_gemm1h<<<(N + 31) / 32, 256, 0, stream>>>(xagg, W1, b1, h, hh, nrm, N);

    // ---- layer 2 (reuses layer-1 CSR; fp16 h gathers) ----
    k_att2csr<<<nBlocks4, 256, 0, stream>>>(h, hh, rowptr, counts, nrm, edata,
                                            w2csr, dinv2, N);
    k_gemm2<<<(N + 31) / 32, 256, 0, stream>>>(hh, W2, g, N);
    k_gather2<<<nBlocks4, 256, 0, stream>>>(g, rowptr, counts, dinv2, b2, edata, w2csr,
                                            out, N);
}

// Round 9
// 473.850 us; speedup vs baseline: 2.4437x; 1.0009x over previous
//
#include <hip/hip_runtime.h>
#include <hip/hip_bf16.h>
#include <hip/hip_fp16.h>

#define NFEAT 128
#define NHID  256
#define NCLASS 40
#define THRESH 0.1f
#define FEPS   1e-8f
#define GUARD  1e-3f

struct h2x2 { __half2 a, b; };   // 8-byte packed 4x fp16

typedef _Float16 v2h __attribute__((ext_vector_type(2)));

// fdot2: s += dot(2xfp16, 2xfp16) in one VALU op where available
__device__ __forceinline__ float dot2acc(unsigned int a, unsigned int b, float s) {
#if __has_builtin(__builtin_amdgcn_fdot2)
    return __builtin_amdgcn_fdot2(__builtin_bit_cast(v2h, a),
                                  __builtin_bit_cast(v2h, b), s, false);
#else
    float2 fa = __half22float2(__builtin_bit_cast(__half2, a));
    float2 fb = __half22float2(__builtin_bit_cast(__half2, b));
    return s + fa.x * fb.x + fa.y * fb.y;
#endif
}

__device__ __forceinline__ float waveSum(float v) {
#pragma unroll
    for (int off = 32; off > 0; off >>= 1) v += __shfl_xor(v, off, 64);
    return v;
}

__device__ __forceinline__ float halfSum(float v) {
#pragma unroll
    for (int off = 16; off > 0; off >>= 1) v += __shfl_xor(v, off, 64);
    return v;
}

__device__ __forceinline__ float qSum16(float v) {
#pragma unroll
    for (int off = 8; off > 0; off >>= 1) v += __shfl_xor(v, off, 64);
    return v;
}

// ---- prep: nrm + normalized fp16 xn + zero-init deg/counts (wave per node) ----
__global__ void k_prep(const float* __restrict__ x, __half2* __restrict__ xn,
                       float* __restrict__ nrm, float* __restrict__ deg,
                       int* __restrict__ counts, int N) {
    int r = (blockIdx.x * blockDim.x + threadIdx.x) >> 6;
    int lane = threadIdx.x & 63;
    if (r >= N) return;
    float2 a = ((const float2*)(x + (size_t)r * NFEAT))[lane];
    float s = waveSum(a.x * a.x + a.y * a.y);
    float nr = fmaxf(sqrtf(s), FEPS);
    float inv = 1.0f / nr;
    xn[(size_t)r * (NFEAT / 2) + lane] = __floats2half2_rn(a.x * inv, a.y * inv);
    if (lane == 0) {
        nrm[r] = nr;
        deg[r] = 0.0f;
        counts[r] = 0;
    }
}

// ---- att1: 4 edges/wave (16-lane groups) over normalized fp16 x; fdot2 ----
__global__ void k_att1(const float* __restrict__ xf, const __half2* __restrict__ xn,
                       const int* __restrict__ row, const int* __restrict__ col,
                       const float* __restrict__ nrm,
                       float* __restrict__ w1, float* __restrict__ deg,
                       int* __restrict__ counts, int E) {
    int wid = (blockIdx.x * blockDim.x + threadIdx.x) >> 6;
    int lane = threadIdx.x & 63;
    int g = lane >> 4, l16 = lane & 15;
    int e = wid * 4 + g;
    if (e >= E) return;
    int r = row[e], c = col[e];
    uint4 av = ((const uint4*)(xn + (size_t)r * (NFEAT / 2)))[l16];
    uint4 bv = ((const uint4*)(xn + (size_t)c * (NFEAT / 2)))[l16];
    float s = 0.f;
    s = dot2acc(av.x, bv.x, s);
    s = dot2acc(av.y, bv.y, s);
    s = dot2acc(av.z, bv.z, s);
    s = dot2acc(av.w, bv.w, s);
    float sims = qSum16(s);
    if (__builtin_expect(fabsf(sims - THRESH) < GUARD, 0)) {
        const float4* fr = (const float4*)(xf + (size_t)r * NFEAT);
        const float4* fc = (const float4*)(xf + (size_t)c * NFEAT);
        float4 a0 = fr[l16], a1 = fr[l16 + 16];
        float4 b0 = fc[l16], b1 = fc[l16 + 16];
        float s2 = qSum16(a0.x * b0.x + a0.y * b0.y + a0.z * b0.z + a0.w * b0.w +
                          a1.x * b1.x + a1.y * b1.y + a1.z * b1.z + a1.w * b1.w);
        sims = s2 / (nrm[r] * nrm[c]);
    }
    if (l16 == 0) {
        float w = (sims >= THRESH && r != c) ? sims : 0.0f;
        w1[e] = w;
        if (w != 0.0f) {
            unsafeAtomicAdd(&deg[r], w);
            atomicAdd(&counts[r], 1);
        }
    }
}

// ---- exclusive scan of counts -> rowptr (3-kernel, N <= 512*256) ----
__global__ __launch_bounds__(256) void k_scan1(const int* __restrict__ counts,
                                               int* __restrict__ rowptr,
                                               int* __restrict__ bsum, int N) {
    __shared__ int tmp[256];
    int t = threadIdx.x, i = blockIdx.x * 256 + t;
    int v = (i < N) ? counts[i] : 0;
    tmp[t] = v;
    __syncthreads();
    for (int off = 1; off < 256; off <<= 1) {
        int add = (t >= off) ? tmp[t - off] : 0;
        __syncthreads();
        tmp[t] += add;
        __syncthreads();
    }
    if (i < N) rowptr[i] = tmp[t] - v;
    if (t == 255) bsum[blockIdx.x] = tmp[t];
}

__global__ __launch_bounds__(512) void k_scan2(int* __restrict__ bsum, int nb) {
    __shared__ int tmp[512];
    int t = threadIdx.x;
    int v = (t < nb) ? bsum[t] : 0;
    tmp[t] = v;
    __syncthreads();
    for (int off = 1; off < 512; off <<= 1) {
        int add = (t >= off) ? tmp[t - off] : 0;
        __syncthreads();
        tmp[t] += add;
        __syncthreads();
    }
    if (t < nb) bsum[t] = tmp[t] - v;
}

__global__ void k_scan3(int* __restrict__ rowptr, const int* __restrict__ bsum, int N) {
    int i = blockIdx.x * 256 + threadIdx.x;
    if (i < N) rowptr[i] += bsum[blockIdx.x];
}

// ---- fill CSR: edata[pos] = (col, norm); dinv computed inline from deg ----
__global__ void k_fill(const int* __restrict__ row, const int* __restrict__ col,
                       const float* __restrict__ wbuf, const float* __restrict__ deg,
                       int* __restrict__ rowptr, int2* __restrict__ edata, int E) {
    int e = blockIdx.x * blockDim.x + threadIdx.x;
    if (e >= E) return;
    float w = wbuf[e];
    if (w == 0.0f) return;
    int r = row[e], c = col[e];
    float dr = 1.0f / sqrtf(1.0f + deg[r]);
    float dc = 1.0f / sqrtf(1.0f + deg[c]);
    float nm = dr * w * dc;
    int pos = atomicAdd(&rowptr[r], 1);
    edata[pos] = make_int2(c, __float_as_int(nm));
}

// ---- gather1: xagg[r] = dinv^2*x[r] + sum_e nm*x[c]  (wave per node, f32) ----
__global__ void k_gather1(const float* __restrict__ xf, const int* __restrict__ rowptr,
                          const int* __restrict__ counts, const float* __restrict__ deg,
                          const int2* __restrict__ edata, float* __restrict__ xagg, int N) {
    int r = (blockIdx.x * blockDim.x + threadIdx.x) >> 6;
    int lane = threadIdx.x & 63;
    if (r >= N) return;
    int cnt = counts[r];
    int start = rowptr[r] - cnt;
    float d = 1.0f / sqrtf(1.0f + deg[r]);
    float2 xa = ((const float2*)(xf + (size_t)r * NFEAT))[lane];
    float2 acc = make_float2(d * d * xa.x, d * d * xa.y);
    for (int k = 0; k < cnt; ++k) {
        int2 ed = edata[start + k];
        float nm = __int_as_float(ed.y);
        float2 xv = ((const float2*)(xf + (size_t)ed.x * NFEAT))[lane];
        acc.x += nm * xv.x;
        acc.y += nm * xv.y;
    }
    ((float2*)(xagg + (size_t)r * NFEAT))[lane] = acc;
}

// ---- gemm1h v4: h = relu(xagg @ W1 + b1); natural-layout xs (conflict-free),
//      16-row W1 chunks (33 KB LDS -> 4 blocks/CU); emits f32 h, fp16 hh, norms ----
__global__ __launch_bounds__(256) void k_gemm1h(const float* __restrict__ xagg,
                                                const float* __restrict__ W1f,
                                                const float* __restrict__ b1f,
                                                float* __restrict__ h,
                                                __half2* __restrict__ hh,
                                                float* __restrict__ nrm2, int N) {
    __shared__ float xs[32][NFEAT + 4];   // [32][132], 16.9 KB; +16B pad per row
    __shared__ float wsh[16][NHID];       // 16 KB W1 chunk
    __shared__ float red[8][4];
    int tid = threadIdx.x;
    int i0 = blockIdx.x * 32;

    // stage xs: coalesced b128 writes, natural layout (bank-conflict-free)
#pragma unroll
    for (int it = 0; it < 4; ++it) {
        int idx4 = it * 256 + tid;
        int n = idx4 >> 5, kq = idx4 & 31;
        int i = i0 + n;
        float4 v = make_float4(0.f, 0.f, 0.f, 0.f);
        if (i < N) v = ((const float4*)(xagg + (size_t)i * NFEAT))[kq];
        *((float4*)&xs[n][kq * 4]) = v;
    }

    int lane = tid & 63, w = tid >> 6;
    int jg = lane & 31, ngl = lane >> 5;
    int ng = w * 2 + ngl;                 // node group 0..7 (4 nodes each)
    int jA = jg * 4;                      // cols jA..+3 and 128+jA..+3

    float acc[4][8];
#pragma unroll
    for (int a = 0; a < 4; ++a)
#pragma unroll
        for (int b = 0; b < 8; ++b) acc[a][b] = 0.f;

    for (int kc = 0; kc < NFEAT; kc += 16) {
        __syncthreads();
        // stage W1 chunk [16][256]: 1024 float4, stride-16B writes
#pragma unroll
        for (int it = 0; it < 4; ++it) {
            int idx4 = it * 256 + tid;
            int kr = idx4 >> 6, jq = idx4 & 63;
            float4 v = ((const float4*)(W1f + (size_t)(kc + kr) * NHID))[jq];
            *((float4*)&wsh[kr][jq * 4]) = v;
        }
        __syncthreads();
#pragma unroll
        for (int kr = 0; kr < 16; kr += 4) {
            // 4 nodes x 4 features, b128 broadcast reads (2 addrs/wave)
            float4 xv[4];
#pragma unroll
            for (int a = 0; a < 4; ++a)
                xv[a] = *((const float4*)&xs[ng * 4 + a][kc + kr]);
#pragma unroll
            for (int t = 0; t < 4; ++t) {
                float4 wa = *((const float4*)&wsh[kr + t][jA]);
                float4 wb = *((const float4*)&wsh[kr + t][128 + jA]);
                float wv[8] = {wa.x, wa.y, wa.z, wa.w, wb.x, wb.y, wb.z, wb.w};
                float xt[4] = {((const float*)&xv[0])[t], ((const float*)&xv[1])[t],
                               ((const float*)&xv[2])[t], ((const float*)&xv[3])[t]};
#pragma unroll
                for (int a = 0; a < 4; ++a)
#pragma unroll
                    for (int b = 0; b < 8; ++b) acc[a][b] += xt[a] * wv[b];
            }
        }
    }

    float bA[8];
#pragma unroll
    for (int q = 0; q < 4; ++q) { bA[q] = b1f[jA + q]; bA[4 + q] = b1f[128 + jA + q]; }

#pragma unroll
    for (int a = 0; a < 4; ++a) {
        int i = i0 + ng * 4 + a;
        float4 va, vb;
        va.x = fmaxf(acc[a][0] + bA[0], 0.f);
        va.y = fmaxf(acc[a][1] + bA[1], 0.f);
        va.z = fmaxf(acc[a][2] + bA[2], 0.f);
        va.w = fmaxf(acc[a][3] + bA[3], 0.f);
        vb.x = fmaxf(acc[a][4] + bA[4], 0.f);
        vb.y = fmaxf(acc[a][5] + bA[5], 0.f);
        vb.z = fmaxf(acc[a][6] + bA[6], 0.f);
        vb.w = fmaxf(acc[a][7] + bA[7], 0.f);
        if (i < N) {
            *((float4*)(h + (size_t)i * NHID + jA)) = va;
            *((float4*)(h + (size_t)i * NHID + 128 + jA)) = vb;
            __half2* hhrow = hh + (size_t)i * (NHID / 2);
            h2x2 pa = { __floats2half2_rn(va.x, va.y), __floats2half2_rn(va.z, va.w) };
            h2x2 pb = { __floats2half2_rn(vb.x, vb.y), __floats2half2_rn(vb.z, vb.w) };
            ((h2x2*)hhrow)[jg] = pa;
            ((h2x2*)(hhrow + 64))[jg] = pb;
        }
        float p = va.x * va.x + va.y * va.y + va.z * va.z + va.w * va.w +
                  vb.x * vb.x + vb.y * vb.y + vb.z * vb.z + vb.w * vb.w;
        p = halfSum(p);
        if (jg == 0) red[ng][a] = p;
    }
    __syncthreads();
    if (tid < 32) {
        int i = i0 + tid;
        if (i < N) nrm2[i] = fmaxf(sqrtf(red[tid >> 2][tid & 3]), FEPS);
    }
}

// ---- att2 over CSR from fp16 h (fdot2); f32 guard recompute; w2csr + dinv2 ----
__global__ void k_att2csr(const float* __restrict__ h, const __half2* __restrict__ hh,
                          const int* __restrict__ rowptr, const int* __restrict__ counts,
                          const float* __restrict__ nrm2, const int2* __restrict__ edata,
                          float* __restrict__ w2csr, float* __restrict__ dinv2, int N) {
    int r = (blockIdx.x * blockDim.x + threadIdx.x) >> 6;
    int lane = threadIdx.x & 63;
    if (r >= N) return;
    int cnt = counts[r];
    int start = rowptr[r] - cnt;
    float deg = 0.f;
    if (cnt > 0) {
        uint2 hr = ((const uint2*)(hh + (size_t)r * (NHID / 2)))[lane];
        float nr = nrm2[r];
        for (int k = 0; k < cnt; ++k) {
            int c = edata[start + k].x;
            uint2 hc = ((const uint2*)(hh + (size_t)c * (NHID / 2)))[lane];
            float s = dot2acc(hr.y, hc.y, dot2acc(hr.x, hc.x, 0.f));
            s = waveSum(s);
            float inv = 1.0f / (nr * nrm2[c]);
            float sims = s * inv;
            if (__builtin_expect(fabsf(sims - THRESH) < GUARD, 0)) {
                float4 fr = ((const float4*)(h + (size_t)r * NHID))[lane];
                float4 fc = ((const float4*)(h + (size_t)c * NHID))[lane];
                float s2 = waveSum(fr.x * fc.x + fr.y * fc.y + fr.z * fc.z + fr.w * fc.w);
                sims = s2 * inv;
            }
            float w2 = (sims >= THRESH) ? sims : 0.f;
            if (lane == 0) w2csr[start + k] = w2;
            deg += w2;
        }
    }
    if (lane == 0) dinv2[r] = 1.0f / sqrtf(1.0f + deg);
}

// ---- gemm2: g = h @ W2; 32 nodes/block; stages fp16 h tile from hh ----
__global__ __launch_bounds__(256) void k_gemm2(const __half2* __restrict__ hh,
                                               const float* __restrict__ W2f,
                                               float* __restrict__ g, int N) {
    __shared__ __half2 hs[32][NHID / 2 + 1];   // [32][129]
    __shared__ float w2s[NHID * NCLASS];       // 40 KB
    int tid = threadIdx.x;
    int i0 = blockIdx.x * 32;
    for (int idx = tid; idx < NHID * NCLASS; idx += 256) w2s[idx] = W2f[idx];
#pragma unroll
    for (int c = 0; c < 8; ++c) {
        int p = c * 256 + tid;
        int n = p >> 6, kp2 = (p & 63) * 2;
        int i = i0 + n;
        h2x2 v = { __floats2half2_rn(0.f, 0.f), __floats2half2_rn(0.f, 0.f) };
        if (i < N) v = ((const h2x2*)(hh + (size_t)i * (NHID / 2)))[p & 63];
        hs[n][kp2] = v.a;
        hs[n][kp2 + 1] = v.b;
    }
    __syncthreads();
    int wv = tid >> 6;
    int lane = tid & 63;
    int n = lane & 31, half = lane >> 5;
    int j0 = wv * 10 + half * 5;
    int i = i0 + n;
    float acc[5] = {0.f, 0.f, 0.f, 0.f, 0.f};
    for (int kp = 0; kp < NHID / 2; ++kp) {
        float2 hf = __half22float2(hs[n][kp]);
        const float* wrow0 = w2s + (2 * kp) * NCLASS + j0;
        const float* wrow1 = w2s + (2 * kp + 1) * NCLASS + j0;
#pragma unroll
        for (int q = 0; q < 5; ++q)
            acc[q] += hf.x * wrow0[q] + hf.y * wrow1[q];
    }
    if (i < N) {
        float* gp = g + (size_t)i * NCLASS + j0;
#pragma unroll
        for (int q = 0; q < 5; ++q) gp[q] = acc[q];
    }
}

// ---- gather2: out[r] = dinv2^2*g[r] + b2 + sum_e dinv2[r]*w2*dinv2[c]*g[c] ----
__global__ void k_gather2(const float* __restrict__ g, const int* __restrict__ rowptr,
                          const int* __restrict__ counts, const float* __restrict__ dinv2,
                          const float* __restrict__ b2f, const int2* __restrict__ edata,
                          const float* __restrict__ w2csr, float* __restrict__ out, int N) {
    int r = (blockIdx.x * blockDim.x + threadIdx.x) >> 6;
    int lane = threadIdx.x & 63;
    if (r >= N || lane >= NCLASS) return;
    int cnt = counts[r];
    int start = rowptr[r] - cnt;
    float dr = dinv2[r];
    float acc = dr * dr * g[(size_t)r * NCLASS + lane] + b2f[lane];
    for (int k = 0; k < cnt; ++k) {
        int c = edata[start + k].x;
        float w2 = w2csr[start + k];
        acc += dr * w2 * dinv2[c] * g[(size_t)c * NCLASS + lane];
    }
    out[(size_t)r * NCLASS + lane] = acc;
}

extern "C" void kernel_launch(void* const* d_in, const int* in_sizes, int n_in,
                              void* d_out, int out_size, void* d_ws, size_t ws_size,
                              hipStream_t stream) {
    const float* x  = (const float*)d_in[0];
    const int* row  = (const int*)d_in[1];
    const int* col  = (const int*)d_in[2];
    const float* W1 = (const float*)d_in[3];
    const float* b1 = (const float*)d_in[4];
    const float* W2 = (const float*)d_in[5];
    const float* b2 = (const float*)d_in[6];
    float* out = (float*)d_out;
    const int N = in_sizes[0] / NFEAT;
    const int E = in_sizes[1];

    // ---- workspace layout (~222 MB peak) ----
    char* ws = (char*)d_ws;
    size_t off = 0;
    auto alloc = [&](size_t bytes) {
        char* p = ws + off;
        off += (bytes + 255) & ~(size_t)255;
        return p;
    };
    float*   xagg   = (float*)alloc((size_t)N * NFEAT * 4);   // g reuses after gemm1h
    float*   h      = (float*)alloc((size_t)N * NHID * 4);
    __half2* hh     = (__half2*)alloc((size_t)N * NHID * 2);  // fp16 h mirror
    __half2* xn     = hh;                                     // normalized fp16 x overlay
    float*   w1buf  = (float*)alloc((size_t)E * 4);
    float*   w2csr  = (float*)alloc((size_t)E * 4);
    int2*    edata  = (int2*)alloc((size_t)E * 8);
    float*   nrm    = (float*)alloc((size_t)N * 4);           // nrm1, then nrm2
    float*   deg    = (float*)alloc((size_t)N * 4);           // degsum layer 1
    float*   dinv2  = (float*)alloc((size_t)N * 4);
    int*     counts = (int*)alloc((size_t)N * 4);
    int*     rowptr = (int*)alloc((size_t)N * 4);
    int*     bsum   = (int*)alloc(512 * 4);
    float*   g      = xagg;

    const int e4Blocks = (E + 15) / 16;   // 4 edges/wave, 4 waves/block
    const int eBlocks1 = (E + 255) / 256;
    const int nBlocks4 = (N + 3) / 4;
    const int scanB    = (N + 255) / 256;

    // ---- layer 1 ----
    k_prep<<<nBlocks4, 256, 0, stream>>>(x, xn, nrm, deg, counts, N);
    k_att1<<<e4Blocks, 256, 0, stream>>>(x, xn, row, col, nrm, w1buf, deg, counts, E);
    k_scan1<<<scanB, 256, 0, stream>>>(counts, rowptr, bsum, N);
    k_scan2<<<1, 512, 0, stream>>>(bsum, scanB);
    k_scan3<<<scanB, 256, 0, stream>>>(rowptr, bsum, N);
    k_fill<<<eBlocks1, 256, 0, stream>>>(row, col, w1buf, deg, rowptr, edata, E);
    k_gather1<<<nBlocks4, 256, 0, stream>>>(x, rowptr, counts, deg, edata, xagg, N);
    k_gemm1h<<<(N + 31) / 32, 256, 0, stream>>>(xagg, W1, b1, h, hh, nrm, N);

    // ---- layer 2 (reuses layer-1 CSR; fp16 h gathers) ----
    k_att2csr<<<nBlocks4, 256, 0, stream>>>(h, hh, rowptr, counts, nrm, edata,
                                            w2csr, dinv2, N);
    k_gemm2<<<(N + 31) / 32, 256, 0, stream>>>(hh, W2, g, N);
    k_gather2<<<nBlocks4, 256, 0, stream>>>(g, rowptr, counts, dinv2, b2, edata, w2csr,
                                            out, N);
}